// Round 6
// baseline (377.195 us; speedup 1.0000x reference)
//
#include <hip/hip_runtime.h>
#include <hip/hip_bf16.h>

#define B 16
#define N 1024
#define F_IN 64
#define H 256
#define ALPHA 0.2f

typedef __attribute__((ext_vector_type(8))) short short8;
typedef __attribute__((ext_vector_type(8))) _Float16 half8;
typedef __attribute__((ext_vector_type(4))) _Float16 half4;
typedef __attribute__((ext_vector_type(4))) float floatx4;

__device__ __forceinline__ unsigned rne_hi(float v) {
    unsigned b = __float_as_uint(v);
    return (b + 0x7FFFu + ((b >> 16) & 1u)) >> 16;
}
__device__ __forceinline__ float bf16val(unsigned hi) { return __uint_as_float(hi << 16); }

__device__ __forceinline__ floatx4 mfma_bf(short8 a, short8 b, floatx4 c) {
    return __builtin_amdgcn_mfma_f32_16x16x32_bf16(a, b, c, 0, 0, 0);
}
__device__ __forceinline__ floatx4 mfma_f16(half8 a, half8 b, floatx4 c) {
    return __builtin_amdgcn_mfma_f32_16x16x32_f16(a, b, c, 0, 0, 0);
}

// ---------------------------------------------------------------------------
// adj [B,N,N] f32 -> bitmask u32: mask32[(b*N+i)*32 + j/32]
__global__ void k_mask(const float* __restrict__ adj, unsigned* __restrict__ mask32) {
    const int lane = threadIdx.x & 63;
    const int wave = blockIdx.x * 4 + (threadIdx.x >> 6);
    const int nwaves = gridDim.x * 4;
    const int words = B * N * (N / 64);
    for (int w = wave; w < words; w += nwaves) {
        float v = adj[(size_t)w * 64 + lane];
        unsigned long long m = __ballot(v > 0.f);
        if (lane == 0) { mask32[2 * w] = (unsigned)m; mask32[2 * w + 1] = (unsigned)(m >> 32); }
    }
}

// ---------------------------------------------------------------------------
// blocks 0-31: W -> transposed split bf16 W_t[c][k]; blocks 32-33: wa = W@a
__global__ __launch_bounds__(256) void k_prep(const float* __restrict__ W0, const float* __restrict__ W1,
                                              const float* __restrict__ a10, const float* __restrict__ a20,
                                              const float* __restrict__ a11, const float* __restrict__ a21,
                                              ushort* __restrict__ wth, ushort* __restrict__ wtl,
                                              float* __restrict__ wa1, float* __restrict__ wa2) {
    __shared__ float ld[64][65];
    const int t = threadIdx.x;
    if (blockIdx.x >= 32) {
        const int l = blockIdx.x - 32;
        const float* W = l ? W1 : W0;
        const float* a1 = l ? a11 : a10;
        const float* a2 = l ? a21 : a20;
        float* a1s = &ld[0][0];
        float* a2s = &ld[32][0];
        a1s[t] = a1[t]; a2s[t] = a2[t];
        __syncthreads();
        float v1 = 0.f, v2 = 0.f;
        for (int c = 0; c < H; c += 4) {
            float4 w = *(const float4*)&W[t * H + c];
            v1 += w.x * a1s[c] + w.y * a1s[c + 1] + w.z * a1s[c + 2] + w.w * a1s[c + 3];
            v2 += w.x * a2s[c] + w.y * a2s[c + 1] + w.z * a2s[c + 2] + w.w * a2s[c + 3];
        }
        wa1[l * H + t] = v1;
        wa2[l * H + t] = v2;
        return;
    }
    const int l = blockIdx.x >> 4;
    const int kt = (blockIdx.x >> 2) & 3, ct = blockIdx.x & 3;
    const float* W = l ? W1 : W0;
#pragma unroll
    for (int e = 0; e < 16; e++) {
        int idx = t + 256 * e;
        int kl = idx >> 6, cl = idx & 63;
        ld[kl][cl] = W[(kt * 64 + kl) * H + ct * 64 + cl];
    }
    __syncthreads();
    ushort* oh = wth + l * H * H;
    ushort* ol = wtl + l * H * H;
#pragma unroll
    for (int e = 0; e < 16; e++) {
        int idx = t + 256 * e;
        int cl = idx >> 6, kl = idx & 63;
        float v = ld[kl][cl];
        unsigned hi = rne_hi(v);
        float lo = v - bf16val(hi);
        oh[(ct * 64 + cl) * H + kt * 64 + kl] = (ushort)hi;
        ol[(ct * 64 + cl) * H + kt * 64 + kl] = (ushort)rne_hi(lo);
    }
}

// ---------------------------------------------------------------------------
// embed: x = nf @ emb_W + b -> split bf16 row-major x_hi/x_lo [B*N][H]
#define EMB_ROWS 8
__global__ __launch_bounds__(256) void k_embed(const float* __restrict__ nf,
                                               const float* __restrict__ W,
                                               const float* __restrict__ bias,
                                               ushort* __restrict__ xhi, ushort* __restrict__ xlo) {
    __shared__ float nfs[F_IN][EMB_ROWS];
    const int row0 = blockIdx.x * EMB_ROWS;
    const int t = threadIdx.x;
    for (int idx = t; idx < EMB_ROWS * F_IN; idx += 256) {
        int r = idx >> 6, f = idx & 63;
        nfs[f][r] = nf[(row0 + r) * F_IN + f];
    }
    __syncthreads();
    const int c = t;
    float acc[EMB_ROWS];
    float bv = bias[c];
#pragma unroll
    for (int r = 0; r < EMB_ROWS; r++) acc[r] = bv;
#pragma unroll 16
    for (int f = 0; f < F_IN; f++) {
        float w = W[f * H + c];
        float4 n0 = *(const float4*)&nfs[f][0];
        float4 n1 = *(const float4*)&nfs[f][4];
        acc[0] += n0.x * w; acc[1] += n0.y * w; acc[2] += n0.z * w; acc[3] += n0.w * w;
        acc[4] += n1.x * w; acc[5] += n1.y * w; acc[6] += n1.z * w; acc[7] += n1.w * w;
    }
#pragma unroll
    for (int r = 0; r < EMB_ROWS; r++) {
        float v = acc[r];
        unsigned hi = rne_hi(v);
        xhi[(size_t)(row0 + r) * H + c] = (ushort)hi;
        xlo[(size_t)(row0 + r) * H + c] = (ushort)rne_hi(v - bf16val(hi));
    }
}

// ---------------------------------------------------------------------------
// h = x @ W (bf16x3 MFMA), fully register-resident, ZERO LDS / ZERO barriers.
// Epilogue: h_t stored f16 [b][c][n] via direct half4 stores (n-contiguous).
// chalf0/w0: exact s1/s2 + per-b s2max atomic.
__global__ __launch_bounds__(256, 4) void k_gemm(const ushort* __restrict__ xhi, const ushort* __restrict__ xlo,
                                                 const ushort* __restrict__ wth, const ushort* __restrict__ wtl,
                                                 const float* __restrict__ wa1, const float* __restrict__ wa2,
                                                 _Float16* __restrict__ ht,
                                                 float* __restrict__ s1, float* __restrict__ s2,
                                                 unsigned* __restrict__ s2maxkey) {
    const int lin = blockIdx.x;
    const int rc = lin >> 1, chalf = lin & 1;
    const int row0 = rc * 32;
    const int t = threadIdx.x;
    const int lane = t & 63, w = t >> 6;
    const int l15 = lane & 15, quad = lane >> 4;
    const int nb = 2 * w;

    const ushort* wthh = wth + (size_t)(chalf * 128) * H;
    const ushort* wtlh = wtl + (size_t)(chalf * 128) * H;
    const ushort* b0h = wthh + (size_t)(nb * 16 + l15) * H + quad * 8;
    const ushort* b1h = wthh + (size_t)((nb + 1) * 16 + l15) * H + quad * 8;
    const ushort* b0l = wtlh + (size_t)(nb * 16 + l15) * H + quad * 8;
    const ushort* b1l = wtlh + (size_t)((nb + 1) * 16 + l15) * H + quad * 8;
    const ushort* ah0 = xhi + (size_t)(row0 + l15) * H + quad * 8;
    const ushort* al0 = xlo + (size_t)(row0 + l15) * H + quad * 8;
    const ushort* ah1 = xhi + (size_t)(row0 + 16 + l15) * H + quad * 8;
    const ushort* al1 = xlo + (size_t)(row0 + 16 + l15) * H + quad * 8;

    floatx4 acc[2][2];
    floatx4 z = {0.f, 0.f, 0.f, 0.f};
    acc[0][0] = z; acc[0][1] = z; acc[1][0] = z; acc[1][1] = z;
    float sp1a = 0.f, sp2a = 0.f, sp1b = 0.f, sp2b = 0.f;

    short8 A0h = *(const short8*)ah0;
    short8 A0l = *(const short8*)al0;
    short8 A1h = *(const short8*)ah1;
    short8 A1l = *(const short8*)al1;
    short8 Bh0 = *(const short8*)b0h;
    short8 Bh1 = *(const short8*)b1h;
    short8 Bl0 = *(const short8*)b0l;
    short8 Bl1 = *(const short8*)b1l;

#pragma unroll
    for (int ks = 0; ks < 8; ks++) {
        short8 nA0h = A0h, nA0l = A0l, nA1h = A1h, nA1l = A1l;
        short8 nBh0 = Bh0, nBh1 = Bh1, nBl0 = Bl0, nBl1 = Bl1;
        if (ks < 7) {
            const int k0n = (ks + 1) * 32;
            nA0h = *(const short8*)(ah0 + k0n);
            nA0l = *(const short8*)(al0 + k0n);
            nA1h = *(const short8*)(ah1 + k0n);
            nA1l = *(const short8*)(al1 + k0n);
            nBh0 = *(const short8*)(b0h + k0n);
            nBh1 = *(const short8*)(b1h + k0n);
            nBl0 = *(const short8*)(b0l + k0n);
            nBl1 = *(const short8*)(b1l + k0n);
        }
        acc[0][0] = mfma_bf(A0h, Bh0, acc[0][0]);
        acc[0][0] = mfma_bf(A0h, Bl0, acc[0][0]);
        acc[0][0] = mfma_bf(A0l, Bh0, acc[0][0]);
        acc[0][1] = mfma_bf(A0h, Bh1, acc[0][1]);
        acc[0][1] = mfma_bf(A0h, Bl1, acc[0][1]);
        acc[0][1] = mfma_bf(A0l, Bh1, acc[0][1]);
        acc[1][0] = mfma_bf(A1h, Bh0, acc[1][0]);
        acc[1][0] = mfma_bf(A1h, Bl0, acc[1][0]);
        acc[1][0] = mfma_bf(A1l, Bh0, acc[1][0]);
        acc[1][1] = mfma_bf(A1h, Bh1, acc[1][1]);
        acc[1][1] = mfma_bf(A1h, Bl1, acc[1][1]);
        acc[1][1] = mfma_bf(A1l, Bh1, acc[1][1]);
        if (chalf == 0 && w == 0) {
            float4 w1a = *(const float4*)(wa1 + ks * 32 + quad * 8);
            float4 w1b = *(const float4*)(wa1 + ks * 32 + quad * 8 + 4);
            float4 w2a = *(const float4*)(wa2 + ks * 32 + quad * 8);
            float4 w2b = *(const float4*)(wa2 + ks * 32 + quad * 8 + 4);
            float wv1[8] = {w1a.x, w1a.y, w1a.z, w1a.w, w1b.x, w1b.y, w1b.z, w1b.w};
            float wv2[8] = {w2a.x, w2a.y, w2a.z, w2a.w, w2b.x, w2b.y, w2b.z, w2b.w};
#pragma unroll
            for (int j = 0; j < 8; j++) {
                float xa = bf16val((ushort)A0h[j]) + bf16val((ushort)A0l[j]);
                float xb = bf16val((ushort)A1h[j]) + bf16val((ushort)A1l[j]);
                sp1a += xa * wv1[j]; sp2a += xa * wv2[j];
                sp1b += xb * wv1[j]; sp2b += xb * wv2[j];
            }
        }
        A0h = nA0h; A0l = nA0l; A1h = nA1h; A1l = nA1l;
        Bh0 = nBh0; Bh1 = nBh1; Bl0 = nBl0; Bl1 = nBl1;
    }

    // ---- epilogue: h_t f16 direct stores (4 n-consecutive per acc reg group) ----
    const int bb = row0 >> 10;
#pragma unroll
    for (int rg = 0; rg < 2; rg++) {
        const int n0 = (row0 & 1023) + rg * 16 + quad * 4;
#pragma unroll
        for (int n2 = 0; n2 < 2; n2++) {
            const int c = chalf * 128 + (nb + n2) * 16 + l15;
            half4 hv;
            hv[0] = (_Float16)acc[rg][n2][0];
            hv[1] = (_Float16)acc[rg][n2][1];
            hv[2] = (_Float16)acc[rg][n2][2];
            hv[3] = (_Float16)acc[rg][n2][3];
            *(half4*)(ht + (((size_t)(bb * H + c)) << 10) + n0) = hv;
        }
    }
    // ---- s1/s2 (exact x.wa) from wave 0 of chalf==0 blocks ----
    if (chalf == 0 && w == 0) {
        sp1a += __shfl_xor(sp1a, 16); sp1a += __shfl_xor(sp1a, 32);
        sp2a += __shfl_xor(sp2a, 16); sp2a += __shfl_xor(sp2a, 32);
        sp1b += __shfl_xor(sp1b, 16); sp1b += __shfl_xor(sp1b, 32);
        sp2b += __shfl_xor(sp2b, 16); sp2b += __shfl_xor(sp2b, 32);
        if (quad == 0) {
            s1[row0 + l15] = sp1a; s2[row0 + l15] = sp2a;
            s1[row0 + 16 + l15] = sp1b; s2[row0 + 16 + l15] = sp2b;
        }
        float m = fmaxf(sp2a, sp2b);
#pragma unroll
        for (int off = 1; off <= 8; off <<= 1) m = fmaxf(m, __shfl_xor(m, off));
        if (lane == 0) {
            unsigned bt = __float_as_uint(m);
            unsigned keyv = (bt & 0x80000000u) ? ~bt : (bt | 0x80000000u);
            atomicMax(&s2maxkey[row0 >> 10], keyv);
        }
    }
}

// ---------------------------------------------------------------------------
// P producer: P[b][i][j] = f16(masked exp(leaky(s1_i+s2_j) - mrow_i)), plus
// fp32 row sums l. 1024 blocks (16 rows each), 16 waves/CU, no MFMA.
__global__ __launch_bounds__(256) void k_pgen(const float* __restrict__ s1, const float* __restrict__ s2,
                                              const unsigned* __restrict__ mask32,
                                              const unsigned* __restrict__ s2maxkey,
                                              _Float16* __restrict__ P, float* __restrict__ lsums) {
    __shared__ float s2s[N];
    const int lin = blockIdx.x;
    const int xcd = lin & 7, q = lin >> 3;           // q 0..127
    const int b = xcd * 2 + (q & 1);
    const int i0 = (q >> 1) * 16;                    // 64 chunks of 16 rows
    const int lane = threadIdx.x & 63, w = threadIdx.x >> 6;

    unsigned key = s2maxkey[b];
    unsigned mb = (key & 0x80000000u) ? (key ^ 0x80000000u) : ~key;
    const float s2max = __uint_as_float(mb);
    const float* s2b = s2 + b * N;
    for (int idx = threadIdx.x; idx < N; idx += 256) s2s[idx] = s2b[idx];
    __syncthreads();

#pragma unroll
    for (int r = 0; r < 4; r++) {
        const int i = i0 + w * 4 + r;
        const float s1v = s1[b * N + i];
        const float tmx = s1v + s2max;
        const float mrow = fmaxf(tmx, ALPHA * tmx);
        const unsigned* mp = mask32 + (size_t)(b * N + i) * 32;
        unsigned* Prow32 = (unsigned*)(P + (((size_t)(b * N + i)) << 10));
        float lacc = 0.f;
#pragma unroll
        for (int it = 0; it < 8; it++) {
            const int j = it * 128 + (lane << 1);
            unsigned mword = mp[j >> 5];
            float2 sv = *(const float2*)&s2s[j];
            float e0 = s1v + sv.x; e0 = fmaxf(e0, ALPHA * e0);
            float e1 = s1v + sv.y; e1 = fmaxf(e1, ALPHA * e1);
            float p0 = __expf(e0 - mrow);
            float p1 = __expf(e1 - mrow);
            p0 = ((mword >> (j & 31)) & 1u) ? p0 : 0.f;
            p1 = ((mword >> ((j & 31) + 1)) & 1u) ? p1 : 0.f;
            union { _Float16 h[2]; unsigned u; } pk;
            pk.h[0] = (_Float16)p0; pk.h[1] = (_Float16)p1;
            lacc += (float)pk.h[0] + (float)pk.h[1];
            Prow32[it * 64 + lane] = pk.u;
        }
#pragma unroll
        for (int off = 1; off <= 32; off <<= 1) lacc += __shfl_xor(lacc, off);
        if (lane == 0) lsums[b * N + i] = lacc;
    }
}

// ---------------------------------------------------------------------------
// GAT: out = relu((P @ h)/l). Pure f16 GEMM: A(P) + B(h_t) global->reg with
// depth-2 prefetch. ZERO LDS, ZERO barriers. 64 i x 128 c per block.
template <int LAST>
__global__ __launch_bounds__(256, 2) void k_gat(const _Float16* __restrict__ P,
                                                const _Float16* __restrict__ ht,
                                                const float* __restrict__ lsums,
                                                float* __restrict__ outf,
                                                ushort* __restrict__ oxhi, ushort* __restrict__ oxlo,
                                                float* __restrict__ psum, float* __restrict__ pmax) {
    const int lin = blockIdx.x;                     // 512 blocks
    const int xcd = lin & 7, sl = lin >> 3;
    const int b = xcd * 2 + (sl & 1);               // batch pinned to XCD pair
    const int chunk = (sl >> 1) & 15;
    const int chalf = sl >> 5;
    const int i0 = chunk * 64;
    const int t = threadIdx.x;
    const int lane = t & 63, w = t >> 6;
    const int l15 = lane & 15, quad = lane >> 4;
    const int nb = 2 * w;

    const _Float16* aP0 = P + (((size_t)(b * N + i0 + l15)) << 10) + quad * 8;
    const _Float16* aP1 = aP0 + (16 << 10);
    const _Float16* aP2 = aP0 + (32 << 10);
    const _Float16* aP3 = aP0 + (48 << 10);
    const _Float16* pB0 = ht + (((size_t)(b * H + chalf * 128 + nb * 16 + l15)) << 10) + quad * 8;
    const _Float16* pB1 = ht + (((size_t)(b * H + chalf * 128 + (nb + 1) * 16 + l15)) << 10) + quad * 8;

    floatx4 acc[4][2];
    floatx4 z = {0.f, 0.f, 0.f, 0.f};
#pragma unroll
    for (int rg = 0; rg < 4; rg++) { acc[rg][0] = z; acc[rg][1] = z; }

    half8 cA0 = *(const half8*)(aP0), cA1 = *(const half8*)(aP1);
    half8 cA2 = *(const half8*)(aP2), cA3 = *(const half8*)(aP3);
    half8 cB0 = *(const half8*)(pB0), cB1 = *(const half8*)(pB1);
    half8 nA0 = *(const half8*)(aP0 + 32), nA1 = *(const half8*)(aP1 + 32);
    half8 nA2 = *(const half8*)(aP2 + 32), nA3 = *(const half8*)(aP3 + 32);
    half8 nB0 = *(const half8*)(pB0 + 32), nB1 = *(const half8*)(pB1 + 32);

#pragma unroll 2
    for (int jt = 0; jt < 32; jt++) {
        const int j2 = (jt + 2 <= 31 ? jt + 2 : 31) * 32;
        half8 fA0 = *(const half8*)(aP0 + j2);
        half8 fA1 = *(const half8*)(aP1 + j2);
        half8 fA2 = *(const half8*)(aP2 + j2);
        half8 fA3 = *(const half8*)(aP3 + j2);
        half8 fB0 = *(const half8*)(pB0 + j2);
        half8 fB1 = *(const half8*)(pB1 + j2);
        acc[0][0] = mfma_f16(cA0, cB0, acc[0][0]);
        acc[1][0] = mfma_f16(cA1, cB0, acc[1][0]);
        acc[2][0] = mfma_f16(cA2, cB0, acc[2][0]);
        acc[3][0] = mfma_f16(cA3, cB0, acc[3][0]);
        acc[0][1] = mfma_f16(cA0, cB1, acc[0][1]);
        acc[1][1] = mfma_f16(cA1, cB1, acc[1][1]);
        acc[2][1] = mfma_f16(cA2, cB1, acc[2][1]);
        acc[3][1] = mfma_f16(cA3, cB1, acc[3][1]);
        cA0 = nA0; cA1 = nA1; cA2 = nA2; cA3 = nA3; cB0 = nB0; cB1 = nB1;
        nA0 = fA0; nA1 = fA1; nA2 = fA2; nA3 = fA3; nB0 = fB0; nB1 = fB1;
    }

    const size_t rbase = (size_t)b * N + i0;
    float inv[4][4];
#pragma unroll
    for (int rg = 0; rg < 4; rg++)
#pragma unroll
        for (int r = 0; r < 4; r++) inv[rg][r] = 1.f / lsums[rbase + rg * 16 + quad * 4 + r];

    float colsum[2] = {0.f, 0.f}, colmax[2] = {-INFINITY, -INFINITY};
#pragma unroll
    for (int rg = 0; rg < 4; rg++)
#pragma unroll
        for (int n2 = 0; n2 < 2; n2++) {
            const int c = chalf * 128 + (nb + n2) * 16 + l15;
#pragma unroll
            for (int r = 0; r < 4; r++) {
                float v = fmaxf(acc[rg][n2][r] * inv[rg][r], 0.f);
                const size_t row = rbase + rg * 16 + quad * 4 + r;
                if (LAST) {
                    outf[row * H + c] = v;
                    colsum[n2] += v;
                    colmax[n2] = fmaxf(colmax[n2], v);
                } else {
                    unsigned hi = rne_hi(v);
                    oxhi[row * H + c] = (ushort)hi;
                    oxlo[row * H + c] = (ushort)rne_hi(v - bf16val(hi));
                }
            }
        }
    if (LAST) {
#pragma unroll
        for (int n2 = 0; n2 < 2; n2++) {
            float s = colsum[n2], m = colmax[n2];
            s += __shfl_xor(s, 16); s += __shfl_xor(s, 32);
            m = fmaxf(m, __shfl_xor(m, 16)); m = fmaxf(m, __shfl_xor(m, 32));
            if (quad == 0) {
                const int c = chalf * 128 + (nb + n2) * 16 + l15;
                psum[(b * 16 + chunk) * H + c] = s;
                pmax[(b * 16 + chunk) * H + c] = m;
            }
        }
    }
}

// ---------------------------------------------------------------------------
// finish mean+max over 16 chunk-partials, then 2-layer MLP -> g[b,:]
__global__ __launch_bounds__(256) void k_pool2(const float* __restrict__ psum,
                                               const float* __restrict__ pmax,
                                               const float* __restrict__ W1, const float* __restrict__ b1,
                                               const float* __restrict__ W2, const float* __restrict__ b2,
                                               float* __restrict__ gout) {
    __shared__ float g_s[H];
    __shared__ float t_s[H];
    const int b = blockIdx.x;
    const int c = threadIdx.x;
    float s = 0.f, m = -INFINITY;
#pragma unroll
    for (int ch = 0; ch < 16; ch++) {
        s += psum[(b * 16 + ch) * H + c];
        m = fmaxf(m, pmax[(b * 16 + ch) * H + c]);
    }
    g_s[c] = s * (1.f / N) + m;
    __syncthreads();
    float a = b1[c];
#pragma unroll 16
    for (int k = 0; k < H; k++) a += g_s[k] * W1[k * H + c];
    t_s[c] = fmaxf(a, 0.f);
    __syncthreads();
    float o = b2[c];
#pragma unroll 16
    for (int k = 0; k < H; k++) o += t_s[k] * W2[k * H + c];
    gout[b * H + c] = o;
}

// ---------------------------------------------------------------------------
extern "C" void kernel_launch(void* const* d_in, const int* in_sizes, int n_in,
                              void* d_out, int out_size, void* d_ws, size_t ws_size,
                              hipStream_t stream) {
    const float* nf    = (const float*)d_in[0];
    const float* adj   = (const float*)d_in[1];
    const float* emb_W = (const float*)d_in[2];
    const float* emb_b = (const float*)d_in[3];
    const float* W0    = (const float*)d_in[4];
    const float* a1_0  = (const float*)d_in[5];
    const float* a2_0  = (const float*)d_in[6];
    const float* W1    = (const float*)d_in[7];
    const float* a1_1  = (const float*)d_in[8];
    const float* a2_1  = (const float*)d_in[9];
    const float* gpW1  = (const float*)d_in[10];
    const float* gpb1  = (const float*)d_in[11];
    const float* gpW2  = (const float*)d_in[12];
    const float* gpb2  = (const float*)d_in[13];

    float* xout = (float*)d_out;
    float* gout = xout + B * N * H;

    char* w = (char*)d_ws;
    ushort* xhi      = (ushort*)(w);                  //  8 MB
    ushort* xlo      = (ushort*)(w + 8388608);        //  8 MB
    _Float16* ht     = (_Float16*)(w + 16777216);     //  8 MB
    _Float16* P      = (_Float16*)(w + 25165824);     // 32 MB
    unsigned* mask32 = (unsigned*)(w + 58720256);     //  2 MB
    float* s1        = (float*)(w + 60817408);
    float* s2        = (float*)(w + 60882944);
    float* lsums     = (float*)(w + 60948480);
    ushort* wth      = (ushort*)(w + 61013504);
    ushort* wtl      = (ushort*)(w + 61275648);
    float* wa1       = (float*)(w + 61537792);
    float* wa2       = (float*)(w + 61539840);
    unsigned* keys   = (unsigned*)(w + 61541888);
    // psum/pmax overlay xhi (dead after gemm<1>; written by gat<1>)
    float* psum      = (float*)(w);
    float* pmax      = (float*)(w + 262144);

    hipMemsetAsync(keys, 0, 128, stream);
    k_mask<<<1024, 256, 0, stream>>>(adj, mask32);
    k_prep<<<34, 256, 0, stream>>>(W0, W1, a1_0, a2_0, a1_1, a2_1, wth, wtl, wa1, wa2);
    k_embed<<<B * N / EMB_ROWS, 256, 0, stream>>>(nf, emb_W, emb_b, xhi, xlo);

    // layer 0
    k_gemm<<<B * N / 32 * 2, 256, 0, stream>>>(xhi, xlo, wth, wtl, wa1, wa2,
                                               ht, s1, s2, keys);
    k_pgen<<<1024, 256, 0, stream>>>(s1, s2, mask32, keys, P, lsums);
    k_gat<0><<<512, 256, 0, stream>>>(P, ht, lsums, nullptr, xhi, xlo, nullptr, nullptr);

    // layer 1
    k_gemm<<<B * N / 32 * 2, 256, 0, stream>>>(xhi, xlo, wth + H * H, wtl + H * H, wa1 + H, wa2 + H,
                                               ht, s1, s2, keys + 16);
    k_pgen<<<1024, 256, 0, stream>>>(s1, s2, mask32, keys + 16, P, lsums);
    k_gat<1><<<512, 256, 0, stream>>>(P, ht, lsums, xout, nullptr, nullptr, psum, pmax);

    // pooling MLP
    k_pool2<<<B, 256, 0, stream>>>(psum, pmax, gpW1, gpb1, gpW2, gpb2, gout);
}

// Round 7
// 292.086 us; speedup vs baseline: 1.2914x; 1.2914x over previous
//
#include <hip/hip_runtime.h>
#include <hip/hip_bf16.h>

#define B 16
#define N 1024
#define F_IN 64
#define H 256
#define ALPHA 0.2f

typedef __attribute__((ext_vector_type(8))) short short8;
typedef __attribute__((ext_vector_type(8))) _Float16 half8;
typedef __attribute__((ext_vector_type(4))) _Float16 half4;
typedef __attribute__((ext_vector_type(4))) float floatx4;

__device__ __forceinline__ unsigned rne_hi(float v) {
    unsigned b = __float_as_uint(v);
    return (b + 0x7FFFu + ((b >> 16) & 1u)) >> 16;
}
__device__ __forceinline__ float bf16val(unsigned hi) { return __uint_as_float(hi << 16); }

__device__ __forceinline__ floatx4 mfma_bf(short8 a, short8 b, floatx4 c) {
    return __builtin_amdgcn_mfma_f32_16x16x32_bf16(a, b, c, 0, 0, 0);
}
__device__ __forceinline__ floatx4 mfma_f16(half8 a, half8 b, floatx4 c) {
    return __builtin_amdgcn_mfma_f32_16x16x32_f16(a, b, c, 0, 0, 0);
}

// ---------------------------------------------------------------------------
// adj [B,N,N] f32 -> TRANSPOSED bitmask: maskT[(b*32 + jt)*1024 + i]
__global__ void k_mask(const float* __restrict__ adj, unsigned* __restrict__ maskT) {
    const int lane = threadIdx.x & 63;
    const int wave = blockIdx.x * 4 + (threadIdx.x >> 6);
    const int nwaves = gridDim.x * 4;
    const int words = B * N * (N / 64);
    for (int w = wave; w < words; w += nwaves) {
        float v = adj[(size_t)w * 64 + lane];
        unsigned long long m = __ballot(v > 0.f);
        if (lane == 0) {
            int jw = w & 15, i = (w >> 4) & 1023, b = w >> 14;
            maskT[(size_t)(b * 32 + 2 * jw) * 1024 + i] = (unsigned)m;
            maskT[(size_t)(b * 32 + 2 * jw + 1) * 1024 + i] = (unsigned)(m >> 32);
        }
    }
}

// ---------------------------------------------------------------------------
// blocks 0-31: W -> split-bf16 B-frag order wB[l][ct][ks][lane][8]
// blocks 32-33: wa = W@a
__global__ __launch_bounds__(256) void k_prep(const float* __restrict__ W0, const float* __restrict__ W1,
                                              const float* __restrict__ a10, const float* __restrict__ a20,
                                              const float* __restrict__ a11, const float* __restrict__ a21,
                                              ushort* __restrict__ wBh, ushort* __restrict__ wBl,
                                              float* __restrict__ wa1, float* __restrict__ wa2) {
    __shared__ float lds[256 * 17];
    const int t = threadIdx.x;
    if (blockIdx.x >= 32) {
        const int l = blockIdx.x - 32;
        const float* W = l ? W1 : W0;
        const float* a1 = l ? a11 : a10;
        const float* a2 = l ? a21 : a10;
        a2 = l ? a21 : a20;
        float* a1s = lds;
        float* a2s = lds + 256;
        a1s[t] = a1[t]; a2s[t] = a2[t];
        __syncthreads();
        float v1 = 0.f, v2 = 0.f;
        for (int c = 0; c < H; c += 4) {
            float4 w = *(const float4*)&W[t * H + c];
            v1 += w.x * a1s[c] + w.y * a1s[c + 1] + w.z * a1s[c + 2] + w.w * a1s[c + 3];
            v2 += w.x * a2s[c] + w.y * a2s[c + 1] + w.z * a2s[c + 2] + w.w * a2s[c + 3];
        }
        wa1[l * H + t] = v1;
        wa2[l * H + t] = v2;
        return;
    }
    const int l = blockIdx.x >> 4, ct = blockIdx.x & 15;
    const float* W = l ? W1 : W0;
#pragma unroll
    for (int rep = 0; rep < 16; rep++) {
        int idx = rep * 256 + t;
        int k = idx >> 4, cl = idx & 15;
        lds[k * 17 + cl] = W[k * H + ct * 16 + cl];
    }
    __syncthreads();
    const int lane = t & 63, w = t >> 6;
    const int l15 = lane & 15, quad = lane >> 4;
#pragma unroll
    for (int e = 0; e < 2; e++) {
        const int ks = w * 2 + e;
        short8 bh, bl;
#pragma unroll
        for (int jj = 0; jj < 8; jj++) {
            float v = lds[(ks * 32 + quad * 8 + jj) * 17 + l15];
            unsigned hi = rne_hi(v);
            bh[jj] = (short)hi;
            bl[jj] = (short)rne_hi(v - bf16val(hi));
        }
        size_t o = (size_t)(((l * 16 + ct) * 8 + ks) * 64 + lane) * 8;
        *(short8*)(wBh + o) = bh;
        *(short8*)(wBl + o) = bl;
    }
}

// ---------------------------------------------------------------------------
// embed: x = nf @ emb_W + b -> split bf16 row-major x_hi/x_lo [B*N][H]
#define EMB_ROWS 8
__global__ __launch_bounds__(256) void k_embed(const float* __restrict__ nf,
                                               const float* __restrict__ W,
                                               const float* __restrict__ bias,
                                               ushort* __restrict__ xhi, ushort* __restrict__ xlo) {
    __shared__ float nfs[F_IN][EMB_ROWS];
    const int row0 = blockIdx.x * EMB_ROWS;
    const int t = threadIdx.x;
    for (int idx = t; idx < EMB_ROWS * F_IN; idx += 256) {
        int r = idx >> 6, f = idx & 63;
        nfs[f][r] = nf[(row0 + r) * F_IN + f];
    }
    __syncthreads();
    const int c = t;
    float acc[EMB_ROWS];
    float bv = bias[c];
#pragma unroll
    for (int r = 0; r < EMB_ROWS; r++) acc[r] = bv;
#pragma unroll 16
    for (int f = 0; f < F_IN; f++) {
        float w = W[f * H + c];
        float4 n0 = *(const float4*)&nfs[f][0];
        float4 n1 = *(const float4*)&nfs[f][4];
        acc[0] += n0.x * w; acc[1] += n0.y * w; acc[2] += n0.z * w; acc[3] += n0.w * w;
        acc[4] += n1.x * w; acc[5] += n1.y * w; acc[6] += n1.z * w; acc[7] += n1.w * w;
    }
#pragma unroll
    for (int r = 0; r < EMB_ROWS; r++) {
        float v = acc[r];
        unsigned hi = rne_hi(v);
        xhi[(size_t)(row0 + r) * H + c] = (ushort)hi;
        xlo[(size_t)(row0 + r) * H + c] = (ushort)rne_hi(v - bf16val(hi));
    }
}

// ---------------------------------------------------------------------------
// h = x @ W (bf16x3). x staged to LDS in A-frag order (1 barrier), W read as
// coalesced B-frags from global, zero per-ks barriers. h stored to hB in
// B-frag order via LDS transpose. chalf0/w0: exact s1/s2 + s2max.
#define XS(hl, it, ks) ((((hl) * 2 + (it)) * 8 + (ks)) * 520)
__global__ __launch_bounds__(256, 3) void k_gemm(const ushort* __restrict__ xhi, const ushort* __restrict__ xlo,
                                                 const ushort* __restrict__ wBh, const ushort* __restrict__ wBl,
                                                 const float* __restrict__ wa1, const float* __restrict__ wa2,
                                                 _Float16* __restrict__ hB,
                                                 float* __restrict__ s1, float* __restrict__ s2,
                                                 unsigned* __restrict__ s2maxkey) {
    __shared__ __align__(16) ushort sm[16640];      // x frags; reused for transpose
    const int lin = blockIdx.x;
    const int rc = lin >> 1, chalf = lin & 1;
    const int row0 = rc * 32;
    const int t = threadIdx.x;
    const int lane = t & 63, w = t >> 6;
    const int l15 = lane & 15, quad = lane >> 4;

    // ---- stage x (hi+lo) into LDS in A-frag order ----
#pragma unroll
    for (int hl = 0; hl < 2; hl++) {
        const ushort* src = hl ? xlo : xhi;
#pragma unroll
        for (int pass = 0; pass < 4; pass++) {
            int idx = pass * 256 + t;
            int row_l = idx >> 5, k8 = idx & 31;
            short8 v = *(const short8*)(src + (size_t)(row0 + row_l) * H + k8 * 8);
            int it = row_l >> 4, lf = row_l & 15, ks = k8 >> 2, qd = k8 & 3;
            *(short8*)(sm + XS(hl, it, ks) + (qd * 16 + lf) * 8) = v;
        }
    }
    __syncthreads();

    const int ct0 = chalf * 8 + 2 * w;
    const ushort* pB0h = wBh + (size_t)((ct0 * 8) * 64 + lane) * 8;
    const ushort* pB1h = wBh + (size_t)(((ct0 + 1) * 8) * 64 + lane) * 8;
    const ushort* pB0l = wBl + (size_t)((ct0 * 8) * 64 + lane) * 8;
    const ushort* pB1l = wBl + (size_t)(((ct0 + 1) * 8) * 64 + lane) * 8;

    floatx4 acc[2][2];
    floatx4 z = {0.f, 0.f, 0.f, 0.f};
    acc[0][0] = z; acc[0][1] = z; acc[1][0] = z; acc[1][1] = z;
    float sp1a = 0.f, sp2a = 0.f, sp1b = 0.f, sp2b = 0.f;

    short8 Bh0 = *(const short8*)(pB0h);
    short8 Bh1 = *(const short8*)(pB1h);
    short8 Bl0 = *(const short8*)(pB0l);
    short8 Bl1 = *(const short8*)(pB1l);

#pragma unroll
    for (int ks = 0; ks < 8; ks++) {
        short8 nBh0 = Bh0, nBh1 = Bh1, nBl0 = Bl0, nBl1 = Bl1;
        if (ks < 7) {
            const int o = (ks + 1) * 512;
            nBh0 = *(const short8*)(pB0h + o);
            nBh1 = *(const short8*)(pB1h + o);
            nBl0 = *(const short8*)(pB0l + o);
            nBl1 = *(const short8*)(pB1l + o);
        }
        short8 A0h = *(const short8*)(sm + XS(0, 0, ks) + lane * 8);
        short8 A0l = *(const short8*)(sm + XS(1, 0, ks) + lane * 8);
        short8 A1h = *(const short8*)(sm + XS(0, 1, ks) + lane * 8);
        short8 A1l = *(const short8*)(sm + XS(1, 1, ks) + lane * 8);
        acc[0][0] = mfma_bf(A0h, Bh0, acc[0][0]);
        acc[0][0] = mfma_bf(A0h, Bl0, acc[0][0]);
        acc[0][0] = mfma_bf(A0l, Bh0, acc[0][0]);
        acc[0][1] = mfma_bf(A0h, Bh1, acc[0][1]);
        acc[0][1] = mfma_bf(A0h, Bl1, acc[0][1]);
        acc[0][1] = mfma_bf(A0l, Bh1, acc[0][1]);
        acc[1][0] = mfma_bf(A1h, Bh0, acc[1][0]);
        acc[1][0] = mfma_bf(A1h, Bl0, acc[1][0]);
        acc[1][0] = mfma_bf(A1l, Bh0, acc[1][0]);
        acc[1][1] = mfma_bf(A1h, Bh1, acc[1][1]);
        acc[1][1] = mfma_bf(A1h, Bl1, acc[1][1]);
        acc[1][1] = mfma_bf(A1l, Bh1, acc[1][1]);
        if (chalf == 0 && w == 0) {
            float4 w1a = *(const float4*)(wa1 + ks * 32 + quad * 8);
            float4 w1b = *(const float4*)(wa1 + ks * 32 + quad * 8 + 4);
            float4 w2a = *(const float4*)(wa2 + ks * 32 + quad * 8);
            float4 w2b = *(const float4*)(wa2 + ks * 32 + quad * 8 + 4);
            float wv1[8] = {w1a.x, w1a.y, w1a.z, w1a.w, w1b.x, w1b.y, w1b.z, w1b.w};
            float wv2[8] = {w2a.x, w2a.y, w2a.z, w2a.w, w2b.x, w2b.y, w2b.z, w2b.w};
#pragma unroll
            for (int j = 0; j < 8; j++) {
                float xa = bf16val((ushort)A0h[j]) + bf16val((ushort)A0l[j]);
                float xb = bf16val((ushort)A1h[j]) + bf16val((ushort)A1l[j]);
                sp1a += xa * wv1[j]; sp2a += xa * wv2[j];
                sp1b += xb * wv1[j]; sp2b += xb * wv2[j];
            }
        }
        Bh0 = nBh0; Bh1 = nBh1; Bl0 = nBl0; Bl1 = nBl1;
    }

    // ---- epilogue: f16 + LDS transpose -> B-frag order hB stores ----
    __syncthreads();
    _Float16* trc = (_Float16*)sm;              // [c_local(128)][40]
#pragma unroll
    for (int rg = 0; rg < 2; rg++) {
#pragma unroll
        for (int n2 = 0; n2 < 2; n2++) {
            const int c_l = (2 * w + n2) * 16 + l15;
            half4 hv;
            hv[0] = (_Float16)acc[rg][n2][0];
            hv[1] = (_Float16)acc[rg][n2][1];
            hv[2] = (_Float16)acc[rg][n2][2];
            hv[3] = (_Float16)acc[rg][n2][3];
            *(half4*)(trc + c_l * 40 + rg * 16 + quad * 4) = hv;
        }
    }
    __syncthreads();
    {
        const int ct_l = t >> 5, sub = t & 31;
        const int bb = row0 >> 10, jt = (row0 >> 5) & 31;
        _Float16* dst = hB + (size_t)(((bb * 16 + chalf * 8 + ct_l) * 32 + jt) * 64) * 8;
#pragma unroll
        for (int rep = 0; rep < 2; rep++) {
            int lo = sub + rep * 32;
            int qd = lo >> 4, lf = lo & 15;
            half8 hv = *(const half8*)(trc + (ct_l * 16 + lf) * 40 + qd * 8);
            *(half8*)(dst + lo * 8) = hv;
        }
    }
    // ---- s1/s2 (exact x.wa) ----
    if (chalf == 0 && w == 0) {
        sp1a += __shfl_xor(sp1a, 16); sp1a += __shfl_xor(sp1a, 32);
        sp2a += __shfl_xor(sp2a, 16); sp2a += __shfl_xor(sp2a, 32);
        sp1b += __shfl_xor(sp1b, 16); sp1b += __shfl_xor(sp1b, 32);
        sp2b += __shfl_xor(sp2b, 16); sp2b += __shfl_xor(sp2b, 32);
        if (quad == 0) {
            s1[row0 + l15] = sp1a; s2[row0 + l15] = sp2a;
            s1[row0 + 16 + l15] = sp1b; s2[row0 + 16 + l15] = sp2b;
        }
        float m = fmaxf(sp2a, sp2b);
#pragma unroll
        for (int off = 1; off <= 8; off <<= 1) m = fmaxf(m, __shfl_xor(m, off));
        if (lane == 0) {
            unsigned bt = __float_as_uint(m);
            unsigned keyv = (bt & 0x80000000u) ? ~bt : (bt | 0x80000000u);
            atomicMax(&s2maxkey[row0 >> 10], keyv);
        }
    }
}

// ---------------------------------------------------------------------------
// P producer in A-FRAG order: pA[b][it][jt][lane][8]; each wave owns a 16x32
// tile per jt (coalesced 1KB stores); fused fp32 row sums.
__global__ __launch_bounds__(256) void k_pgen(const float* __restrict__ s1, const float* __restrict__ s2,
                                              const unsigned* __restrict__ maskT,
                                              const unsigned* __restrict__ s2maxkey,
                                              _Float16* __restrict__ pA, float* __restrict__ lsums) {
    __shared__ float s2s[N];
    __shared__ float lp[4][16];
    const int lin = blockIdx.x;                    // 512 blocks
    const int xcd = lin & 7, sl = lin >> 3;
    const int b = xcd * 2 + (sl & 1);
    const int itg = sl >> 1;                       // 0..31
    const int t = threadIdx.x;
    const int lane = t & 63, w = t >> 6;
    const int l15 = lane & 15, quad = lane >> 4;

    unsigned key = s2maxkey[b];
    unsigned mb = (key & 0x80000000u) ? (key ^ 0x80000000u) : ~key;
    const float s2max = __uint_as_float(mb);
    for (int idx = t; idx < N; idx += 256) s2s[idx] = s2[b * N + idx];
    __syncthreads();

    const int it = itg * 2 + (w & 1);
    const int jt0 = (w >> 1) * 16;
    const int i = it * 16 + l15;
    const float s1v = s1[b * N + i];
    const float tmx = s1v + s2max;
    const float mrow = fmaxf(tmx, ALPHA * tmx);
    const unsigned* mtp = maskT + (size_t)(b * 32) * 1024 + i;
    _Float16* pdst = pA + (size_t)(((b * 64 + it) * 32 + jt0) * 64) * 8 + lane * 8;
    float lacc = 0.f;

    for (int jl = 0; jl < 16; jl++) {
        const int jt = jt0 + jl;
        unsigned mw = mtp[(size_t)jt << 10];
        float4 sa = *(const float4*)&s2s[jt * 32 + quad * 8];
        float4 sb = *(const float4*)&s2s[jt * 32 + quad * 8 + 4];
        float sv[8] = {sa.x, sa.y, sa.z, sa.w, sb.x, sb.y, sb.z, sb.w};
        union { _Float16 h[8]; half8 v; } pk;
#pragma unroll
        for (int jj = 0; jj < 8; jj++) {
            float e = s1v + sv[jj];
            e = fmaxf(e, ALPHA * e);
            float p = __expf(e - mrow);
            p = ((mw >> (quad * 8 + jj)) & 1u) ? p : 0.f;
            pk.h[jj] = (_Float16)p;
            lacc += (float)pk.h[jj];
        }
        *(half8*)(pdst + (size_t)jl * 512) = pk.v;
    }
    lacc += __shfl_xor(lacc, 16);
    lacc += __shfl_xor(lacc, 32);
    if (quad == 0) lp[w][l15] = lacc;
    __syncthreads();
    if (t < 32) {
        int itl = t >> 4, lf = t & 15;
        float tot = lp[itl][lf] + lp[2 + itl][lf];
        lsums[b * N + (itg * 2 + itl) * 16 + lf] = tot;
    }
}

// ---------------------------------------------------------------------------
// GAT: out = relu((P @ h)/l). Pure f16 GEMM, ALL loads lane-sequential frag
// blocks (1KB coalesced). Zero LDS/barriers, depth-2 prefetch. 64i x 128c.
template <int LAST>
__global__ __launch_bounds__(256, 2) void k_gat(const _Float16* __restrict__ pA,
                                                const _Float16* __restrict__ hB,
                                                const float* __restrict__ lsums,
                                                float* __restrict__ outf,
                                                ushort* __restrict__ oxhi, ushort* __restrict__ oxlo,
                                                float* __restrict__ psum, float* __restrict__ pmax) {
    const int lin = blockIdx.x;                     // 512 blocks
    const int xcd = lin & 7, sl = lin >> 3;
    const int b = xcd * 2 + (sl & 1);
    const int chunk = (sl >> 1) & 15;
    const int chalf = sl >> 5;
    const int i0 = chunk * 64;
    const int t = threadIdx.x;
    const int lane = t & 63, w = t >> 6;
    const int l15 = lane & 15, quad = lane >> 4;
    const int nb = 2 * w;
    const int ct0 = chalf * 8 + nb;

    const _Float16* pa0 = pA + (size_t)((b * 64 + chunk * 4 + 0) * 32 * 64) * 8 + lane * 8;
    const _Float16* pa1 = pA + (size_t)((b * 64 + chunk * 4 + 1) * 32 * 64) * 8 + lane * 8;
    const _Float16* pa2 = pA + (size_t)((b * 64 + chunk * 4 + 2) * 32 * 64) * 8 + lane * 8;
    const _Float16* pa3 = pA + (size_t)((b * 64 + chunk * 4 + 3) * 32 * 64) * 8 + lane * 8;
    const _Float16* pb0 = hB + (size_t)((b * 16 + ct0) * 32 * 64) * 8 + lane * 8;
    const _Float16* pb1 = hB + (size_t)((b * 16 + ct0 + 1) * 32 * 64) * 8 + lane * 8;

    floatx4 acc[4][2];
    floatx4 z = {0.f, 0.f, 0.f, 0.f};
#pragma unroll
    for (int rg = 0; rg < 4; rg++) { acc[rg][0] = z; acc[rg][1] = z; }

    half8 cA0 = *(const half8*)(pa0), cA1 = *(const half8*)(pa1);
    half8 cA2 = *(const half8*)(pa2), cA3 = *(const half8*)(pa3);
    half8 cB0 = *(const half8*)(pb0), cB1 = *(const half8*)(pb1);
    half8 nA0 = *(const half8*)(pa0 + 512), nA1 = *(const half8*)(pa1 + 512);
    half8 nA2 = *(const half8*)(pa2 + 512), nA3 = *(const half8*)(pa3 + 512);
    half8 nB0 = *(const half8*)(pb0 + 512), nB1 = *(const half8*)(pb1 + 512);

#pragma unroll 2
    for (int jt = 0; jt < 32; jt++) {
        const int j2 = (jt + 2 <= 31 ? jt + 2 : 31) * 512;
        half8 fA0 = *(const half8*)(pa0 + j2);
        half8 fA1 = *(const half8*)(pa1 + j2);
        half8 fA2 = *(const half8*)(pa2 + j2);
        half8 fA3 = *(const half8*)(pa3 + j2);
        half8 fB0 = *(const half8*)(pb0 + j2);
        half8 fB1 = *(const half8*)(pb1 + j2);
        acc[0][0] = mfma_f16(cA0, cB0, acc[0][0]);
        acc[1][0] = mfma_f16(cA1, cB0, acc[1][0]);
        acc[2][0] = mfma_f16(cA2, cB0, acc[2][0]);
        acc[3][0] = mfma_f16(cA3, cB0, acc[3][0]);
        acc[0][1] = mfma_f16(cA0, cB1, acc[0][1]);
        acc[1][1] = mfma_f16(cA1, cB1, acc[1][1]);
        acc[2][1] = mfma_f16(cA2, cB1, acc[2][1]);
        acc[3][1] = mfma_f16(cA3, cB1, acc[3][1]);
        cA0 = nA0; cA1 = nA1; cA2 = nA2; cA3 = nA3; cB0 = nB0; cB1 = nB1;
        nA0 = fA0; nA1 = fA1; nA2 = fA2; nA3 = fA3; nB0 = fB0; nB1 = fB1;
    }

    const size_t rbase = (size_t)b * N + i0;
    float inv[4][4];
#pragma unroll
    for (int rg = 0; rg < 4; rg++)
#pragma unroll
        for (int r = 0; r < 4; r++) inv[rg][r] = 1.f / lsums[rbase + rg * 16 + quad * 4 + r];

    float colsum[2] = {0.f, 0.f}, colmax[2] = {-INFINITY, -INFINITY};
#pragma unroll
    for (int rg = 0; rg < 4; rg++)
#pragma unroll
        for (int n2 = 0; n2 < 2; n2++) {
            const int c = (ct0 + n2) * 16 + l15;
#pragma unroll
            for (int r = 0; r < 4; r++) {
                float v = fmaxf(acc[rg][n2][r] * inv[rg][r], 0.f);
                const size_t row = rbase + rg * 16 + quad * 4 + r;
                if (LAST) {
                    outf[row * H + c] = v;
                    colsum[n2] += v;
                    colmax[n2] = fmaxf(colmax[n2], v);
                } else {
                    unsigned hi = rne_hi(v);
                    oxhi[row * H + c] = (ushort)hi;
                    oxlo[row * H + c] = (ushort)rne_hi(v - bf16val(hi));
                }
            }
        }
    if (LAST) {
#pragma unroll
        for (int n2 = 0; n2 < 2; n2++) {
            float s = colsum[n2], m = colmax[n2];
            s += __shfl_xor(s, 16); s += __shfl_xor(s, 32);
            m = fmaxf(m, __shfl_xor(m, 16)); m = fmaxf(m, __shfl_xor(m, 32));
            if (quad == 0) {
                const int c = (ct0 + n2) * 16 + l15;
                psum[(b * 16 + chunk) * H + c] = s;
                pmax[(b * 16 + chunk) * H + c] = m;
            }
        }
    }
}

// ---------------------------------------------------------------------------
// finish mean+max over 16 chunk-partials, then 2-layer MLP -> g[b,:]
__global__ __launch_bounds__(256) void k_pool2(const float* __restrict__ psum,
                                               const float* __restrict__ pmax,
                                               const float* __restrict__ W1, const float* __restrict__ b1,
                                               const float* __restrict__ W2, const float* __restrict__ b2,
                                               float* __restrict__ gout) {
    __shared__ float g_s[H];
    __shared__ float t_s[H];
    const int b = blockIdx.x;
    const int c = threadIdx.x;
    float s = 0.f, m = -INFINITY;
#pragma unroll
    for (int ch = 0; ch < 16; ch++) {
        s += psum[(b * 16 + ch) * H + c];
        m = fmaxf(m, pmax[(b * 16 + ch) * H + c]);
    }
    g_s[c] = s * (1.f / N) + m;
    __syncthreads();
    float a = b1[c];
#pragma unroll 16
    for (int k = 0; k < H; k++) a += g_s[k] * W1[k * H + c];
    t_s[c] = fmaxf(a, 0.f);
    __syncthreads();
    float o = b2[c];
#pragma unroll 16
    for (int k = 0; k < H; k++) o += t_s[k] * W2[k * H + c];
    gout[b * H + c] = o;
}

// ---------------------------------------------------------------------------
extern "C" void kernel_launch(void* const* d_in, const int* in_sizes, int n_in,
                              void* d_out, int out_size, void* d_ws, size_t ws_size,
                              hipStream_t stream) {
    const float* nf    = (const float*)d_in[0];
    const float* adj   = (const float*)d_in[1];
    const float* emb_W = (const float*)d_in[2];
    const float* emb_b = (const float*)d_in[3];
    const float* W0    = (const float*)d_in[4];
    const float* a1_0  = (const float*)d_in[5];
    const float* a2_0  = (const float*)d_in[6];
    const float* W1    = (const float*)d_in[7];
    const float* a1_1  = (const float*)d_in[8];
    const float* a2_1  = (const float*)d_in[9];
    const float* gpW1  = (const float*)d_in[10];
    const float* gpb1  = (const float*)d_in[11];
    const float* gpW2  = (const float*)d_in[12];
    const float* gpb2  = (const float*)d_in[13];

    float* xout = (float*)d_out;
    float* gout = xout + B * N * H;

    char* w = (char*)d_ws;
    ushort* xhi      = (ushort*)(w);                  //  8 MB
    ushort* xlo      = (ushort*)(w + 8388608);        //  8 MB
    _Float16* hB     = (_Float16*)(w + 16777216);     //  8 MB (B-frag order)
    _Float16* pA     = (_Float16*)(w + 25165824);     // 32 MB (A-frag order)
    unsigned* maskT  = (unsigned*)(w + 58720256);     //  2 MB (transposed)
    float* s1        = (float*)(w + 60817408);
    float* s2        = (float*)(w + 60882944);
    float* lsums     = (float*)(w + 60948480);
    ushort* wBh      = (ushort*)(w + 61013504);       // 256 KB (B-frag order)
    ushort* wBl      = (ushort*)(w + 61275648);       // 256 KB
    float* wa1       = (float*)(w + 61537792);
    float* wa2       = (float*)(w + 61539840);
    unsigned* keys   = (unsigned*)(w + 61541888);
    // psum/pmax overlay xhi (dead after gemm<1> staging; written by gat<1>)
    float* psum      = (float*)(w);
    float* pmax      = (float*)(w + 262144);

    hipMemsetAsync(keys, 0, 128, stream);
    k_mask<<<1024, 256, 0, stream>>>(adj, maskT);
    k_prep<<<34, 256, 0, stream>>>(W0, W1, a1_0, a2_0, a1_1, a2_1, wBh, wBl, wa1, wa2);
    k_embed<<<B * N / EMB_ROWS, 256, 0, stream>>>(nf, emb_W, emb_b, xhi, xlo);

    // layer 0
    k_gemm<<<1024, 256, 0, stream>>>(xhi, xlo, wBh, wBl, wa1, wa2, hB, s1, s2, keys);
    k_pgen<<<512, 256, 0, stream>>>(s1, s2, maskT, keys, pA, lsums);
    k_gat<0><<<512, 256, 0, stream>>>(pA, hB, lsums, nullptr, xhi, xlo, nullptr, nullptr);

    // layer 1
    k_gemm<<<1024, 256, 0, stream>>>(xhi, xlo, wBh + 65536, wBl + 65536, wa1 + H, wa2 + H,
                                     hB, s1, s2, keys + 16);
    k_pgen<<<512, 256, 0, stream>>>(s1, s2, maskT, keys + 16, pA, lsums);
    k_gat<1><<<512, 256, 0, stream>>>(pA, hB, lsums, xout, nullptr, nullptr, psum, pmax);

    // pooling MLP
    k_pool2<<<B, 256, 0, stream>>>(psum, pmax, gpW1, gpb1, gpW2, gpb2, gout);
}

// Round 8
// 254.272 us; speedup vs baseline: 1.4834x; 1.1487x over previous
//
#include <hip/hip_runtime.h>
#include <hip/hip_bf16.h>

#define B 16
#define N 1024
#define F_IN 64
#define H 256
#define ALPHA 0.2f

typedef __attribute__((ext_vector_type(8))) short short8;
typedef __attribute__((ext_vector_type(8))) _Float16 half8;
typedef __attribute__((ext_vector_type(4))) _Float16 half4;
typedef __attribute__((ext_vector_type(4))) float floatx4;

__device__ __forceinline__ unsigned rne_hi(float v) {
    unsigned b = __float_as_uint(v);
    return (b + 0x7FFFu + ((b >> 16) & 1u)) >> 16;
}
__device__ __forceinline__ float bf16val(unsigned hi) { return __uint_as_float(hi << 16); }

__device__ __forceinline__ floatx4 mfma_bf(short8 a, short8 b, floatx4 c) {
    return __builtin_amdgcn_mfma_f32_16x16x32_bf16(a, b, c, 0, 0, 0);
}
__device__ __forceinline__ floatx4 mfma_f16(half8 a, half8 b, floatx4 c) {
    return __builtin_amdgcn_mfma_f32_16x16x32_f16(a, b, c, 0, 0, 0);
}

// ---------------------------------------------------------------------------
// Fused front kernel:
//   blocks [0,1024):    adj -> bitmask, plane-packed words (see pgen extract)
//   blocks [1024,1536): embed (32 rows/block, nf in LDS, W col reuse x32)
//   blocks [1536,1570): W -> B-frag split bf16 (32) ; wa = W@a (2)
// mask32[(b*N+i)*32 + jt], bit (k*8+m) <-> j offset m*4+k within the 32-j word
__global__ __launch_bounds__(256) void k_front(const float* __restrict__ adj,
                                               const float* __restrict__ nf,
                                               const float* __restrict__ embW,
                                               const float* __restrict__ embB,
                                               const float* __restrict__ W0, const float* __restrict__ W1,
                                               const float* __restrict__ a10, const float* __restrict__ a20,
                                               const float* __restrict__ a11, const float* __restrict__ a21,
                                               unsigned* __restrict__ mask32,
                                               ushort* __restrict__ xhi, ushort* __restrict__ xlo,
                                               ushort* __restrict__ wBh, ushort* __restrict__ wBl,
                                               float* __restrict__ wa1, float* __restrict__ wa2) {
    __shared__ float lds[256 * 17];
    const int blk = blockIdx.x;
    const int t = threadIdx.x;
    const int lane = t & 63;

    if (blk < 1024) {
        // ---- mask: wave handles 256 j per task via float4 + 4 ballots ----
        const int wv = blk * 4 + (t >> 6);
#pragma unroll 2
        for (int task = wv; task < B * N * 4; task += 4096) {
            const float4 v = *(const float4*)(adj + (size_t)task * 256 + lane * 4);
            unsigned long long b0 = __ballot(v.x > 0.f);
            unsigned long long b1 = __ballot(v.y > 0.f);
            unsigned long long b2 = __ballot(v.z > 0.f);
            unsigned long long b3 = __ballot(v.w > 0.f);
            if (lane < 8) {
                unsigned w0 = (unsigned)((b0 >> (8 * lane)) & 0xff)
                            | ((unsigned)((b1 >> (8 * lane)) & 0xff) << 8)
                            | ((unsigned)((b2 >> (8 * lane)) & 0xff) << 16)
                            | ((unsigned)((b3 >> (8 * lane)) & 0xff) << 24);
                const int jg = task & 3, row = task >> 2;
                mask32[(size_t)row * 32 + jg * 8 + lane] = w0;
            }
        }
        return;
    }
    if (blk < 1536) {
        // ---- embed: 32 rows/block ----
        const int row0 = (blk - 1024) * 32;
        float* nfs = lds;                       // [f][32]
        for (int idx = t; idx < 32 * F_IN; idx += 256) {
            int r = idx >> 6, f = idx & 63;
            nfs[f * 32 + r] = nf[(size_t)(row0 + r) * F_IN + f];
        }
        __syncthreads();
        const int c = t;
        float acc[32];
        const float bv = embB[c];
#pragma unroll
        for (int r = 0; r < 32; r++) acc[r] = bv;
#pragma unroll 8
        for (int f = 0; f < F_IN; f++) {
            const float w = embW[f * H + c];
            const float* nrow = nfs + f * 32;
#pragma unroll
            for (int q = 0; q < 8; q++) {
                float4 n4 = *(const float4*)(nrow + q * 4);
                acc[q * 4 + 0] += n4.x * w;
                acc[q * 4 + 1] += n4.y * w;
                acc[q * 4 + 2] += n4.z * w;
                acc[q * 4 + 3] += n4.w * w;
            }
        }
#pragma unroll
        for (int r = 0; r < 32; r++) {
            float v = acc[r];
            unsigned hi = rne_hi(v);
            xhi[(size_t)(row0 + r) * H + c] = (ushort)hi;
            xlo[(size_t)(row0 + r) * H + c] = (ushort)rne_hi(v - bf16val(hi));
        }
        return;
    }
    // ---- prep ----
    const int pb = blk - 1536;
    if (pb >= 32) {
        const int l = pb - 32;
        const float* W = l ? W1 : W0;
        const float* a1 = l ? a11 : a10;
        const float* a2 = l ? a21 : a20;
        float* a1s = lds;
        float* a2s = lds + 256;
        a1s[t] = a1[t]; a2s[t] = a2[t];
        __syncthreads();
        float v1 = 0.f, v2 = 0.f;
        for (int c = 0; c < H; c += 4) {
            float4 w = *(const float4*)&W[t * H + c];
            v1 += w.x * a1s[c] + w.y * a1s[c + 1] + w.z * a1s[c + 2] + w.w * a1s[c + 3];
            v2 += w.x * a2s[c] + w.y * a2s[c + 1] + w.z * a2s[c + 2] + w.w * a2s[c + 3];
        }
        wa1[l * H + t] = v1;
        wa2[l * H + t] = v2;
        return;
    }
    const int l = pb >> 4, ct = pb & 15;
    const float* W = l ? W1 : W0;
#pragma unroll
    for (int rep = 0; rep < 16; rep++) {
        int idx = rep * 256 + t;
        int k = idx >> 4, cl = idx & 15;
        lds[k * 17 + cl] = W[k * H + ct * 16 + cl];
    }
    __syncthreads();
    const int w = t >> 6;
    const int l15 = lane & 15, quad = lane >> 4;
#pragma unroll
    for (int e = 0; e < 2; e++) {
        const int ks = w * 2 + e;
        short8 bh, bl;
#pragma unroll
        for (int jj = 0; jj < 8; jj++) {
            float v = lds[(ks * 32 + quad * 8 + jj) * 17 + l15];
            unsigned hi = rne_hi(v);
            bh[jj] = (short)hi;
            bl[jj] = (short)rne_hi(v - bf16val(hi));
        }
        size_t o = (size_t)(((l * 16 + ct) * 8 + ks) * 64 + lane) * 8;
        *(short8*)(wBh + o) = bh;
        *(short8*)(wBl + o) = bl;
    }
}

// ---------------------------------------------------------------------------
// h = x @ W (bf16x3). x staged to LDS in A-frag order (1 barrier), W read as
// coalesced B-frags from global, zero per-ks barriers. h stored to hB in
// B-frag order via LDS transpose. chalf0/w0: exact s1/s2 + s2max.
#define XS(hl, it, ks) ((((hl) * 2 + (it)) * 8 + (ks)) * 520)
__global__ __launch_bounds__(256, 3) void k_gemm(const ushort* __restrict__ xhi, const ushort* __restrict__ xlo,
                                                 const ushort* __restrict__ wBh, const ushort* __restrict__ wBl,
                                                 const float* __restrict__ wa1, const float* __restrict__ wa2,
                                                 _Float16* __restrict__ hB,
                                                 float* __restrict__ s1, float* __restrict__ s2,
                                                 unsigned* __restrict__ s2maxkey) {
    __shared__ __align__(16) ushort sm[16640];      // x frags; reused for transpose
    const int lin = blockIdx.x;
    const int rc = lin >> 1, chalf = lin & 1;
    const int row0 = rc * 32;
    const int t = threadIdx.x;
    const int lane = t & 63, w = t >> 6;
    const int l15 = lane & 15, quad = lane >> 4;

    // ---- stage x (hi+lo) into LDS in A-frag order ----
#pragma unroll
    for (int hl = 0; hl < 2; hl++) {
        const ushort* src = hl ? xlo : xhi;
#pragma unroll
        for (int pass = 0; pass < 4; pass++) {
            int idx = pass * 256 + t;
            int row_l = idx >> 5, k8 = idx & 31;
            short8 v = *(const short8*)(src + (size_t)(row0 + row_l) * H + k8 * 8);
            int it = row_l >> 4, lf = row_l & 15, ks = k8 >> 2, qd = k8 & 3;
            *(short8*)(sm + XS(hl, it, ks) + (qd * 16 + lf) * 8) = v;
        }
    }
    __syncthreads();

    const int ct0 = chalf * 8 + 2 * w;
    const ushort* pB0h = wBh + (size_t)((ct0 * 8) * 64 + lane) * 8;
    const ushort* pB1h = wBh + (size_t)(((ct0 + 1) * 8) * 64 + lane) * 8;
    const ushort* pB0l = wBl + (size_t)((ct0 * 8) * 64 + lane) * 8;
    const ushort* pB1l = wBl + (size_t)(((ct0 + 1) * 8) * 64 + lane) * 8;

    floatx4 acc[2][2];
    floatx4 z = {0.f, 0.f, 0.f, 0.f};
    acc[0][0] = z; acc[0][1] = z; acc[1][0] = z; acc[1][1] = z;
    float sp1a = 0.f, sp2a = 0.f, sp1b = 0.f, sp2b = 0.f;

    short8 Bh0 = *(const short8*)(pB0h);
    short8 Bh1 = *(const short8*)(pB1h);
    short8 Bl0 = *(const short8*)(pB0l);
    short8 Bl1 = *(const short8*)(pB1l);

#pragma unroll
    for (int ks = 0; ks < 8; ks++) {
        short8 nBh0 = Bh0, nBh1 = Bh1, nBl0 = Bl0, nBl1 = Bl1;
        if (ks < 7) {
            const int o = (ks + 1) * 512;
            nBh0 = *(const short8*)(pB0h + o);
            nBh1 = *(const short8*)(pB1h + o);
            nBl0 = *(const short8*)(pB0l + o);
            nBl1 = *(const short8*)(pB1l + o);
        }
        short8 A0h = *(const short8*)(sm + XS(0, 0, ks) + lane * 8);
        short8 A0l = *(const short8*)(sm + XS(1, 0, ks) + lane * 8);
        short8 A1h = *(const short8*)(sm + XS(0, 1, ks) + lane * 8);
        short8 A1l = *(const short8*)(sm + XS(1, 1, ks) + lane * 8);
        acc[0][0] = mfma_bf(A0h, Bh0, acc[0][0]);
        acc[0][0] = mfma_bf(A0h, Bl0, acc[0][0]);
        acc[0][0] = mfma_bf(A0l, Bh0, acc[0][0]);
        acc[0][1] = mfma_bf(A0h, Bh1, acc[0][1]);
        acc[0][1] = mfma_bf(A0h, Bl1, acc[0][1]);
        acc[0][1] = mfma_bf(A0l, Bh1, acc[0][1]);
        acc[1][0] = mfma_bf(A1h, Bh0, acc[1][0]);
        acc[1][0] = mfma_bf(A1h, Bl0, acc[1][0]);
        acc[1][0] = mfma_bf(A1l, Bh0, acc[1][0]);
        acc[1][1] = mfma_bf(A1h, Bh1, acc[1][1]);
        acc[1][1] = mfma_bf(A1h, Bl1, acc[1][1]);
        acc[1][1] = mfma_bf(A1l, Bh1, acc[1][1]);
        if (chalf == 0 && w == 0) {
            float4 w1a = *(const float4*)(wa1 + ks * 32 + quad * 8);
            float4 w1b = *(const float4*)(wa1 + ks * 32 + quad * 8 + 4);
            float4 w2a = *(const float4*)(wa2 + ks * 32 + quad * 8);
            float4 w2b = *(const float4*)(wa2 + ks * 32 + quad * 8 + 4);
            float wv1[8] = {w1a.x, w1a.y, w1a.z, w1a.w, w1b.x, w1b.y, w1b.z, w1b.w};
            float wv2[8] = {w2a.x, w2a.y, w2a.z, w2a.w, w2b.x, w2b.y, w2b.z, w2b.w};
#pragma unroll
            for (int j = 0; j < 8; j++) {
                float xa = bf16val((ushort)A0h[j]) + bf16val((ushort)A0l[j]);
                float xb = bf16val((ushort)A1h[j]) + bf16val((ushort)A1l[j]);
                sp1a += xa * wv1[j]; sp2a += xa * wv2[j];
                sp1b += xb * wv1[j]; sp2b += xb * wv2[j];
            }
        }
        Bh0 = nBh0; Bh1 = nBh1; Bl0 = nBl0; Bl1 = nBl1;
    }

    // ---- epilogue: f16 + LDS transpose -> B-frag order hB stores ----
    __syncthreads();
    _Float16* trc = (_Float16*)sm;              // [c_local(128)][40]
#pragma unroll
    for (int rg = 0; rg < 2; rg++) {
#pragma unroll
        for (int n2 = 0; n2 < 2; n2++) {
            const int c_l = (2 * w + n2) * 16 + l15;
            half4 hv;
            hv[0] = (_Float16)acc[rg][n2][0];
            hv[1] = (_Float16)acc[rg][n2][1];
            hv[2] = (_Float16)acc[rg][n2][2];
            hv[3] = (_Float16)acc[rg][n2][3];
            *(half4*)(trc + c_l * 40 + rg * 16 + quad * 4) = hv;
        }
    }
    __syncthreads();
    {
        const int ct_l = t >> 5, sub = t & 31;
        const int bb = row0 >> 10, jt = (row0 >> 5) & 31;
        _Float16* dst = hB + (size_t)(((bb * 16 + chalf * 8 + ct_l) * 32 + jt) * 64) * 8;
#pragma unroll
        for (int rep = 0; rep < 2; rep++) {
            int lo = sub + rep * 32;
            int qd = lo >> 4, lf = lo & 15;
            half8 hv = *(const half8*)(trc + (ct_l * 16 + lf) * 40 + qd * 8);
            *(half8*)(dst + lo * 8) = hv;
        }
    }
    // ---- s1/s2 (exact x.wa) ----
    if (chalf == 0 && w == 0) {
        sp1a += __shfl_xor(sp1a, 16); sp1a += __shfl_xor(sp1a, 32);
        sp2a += __shfl_xor(sp2a, 16); sp2a += __shfl_xor(sp2a, 32);
        sp1b += __shfl_xor(sp1b, 16); sp1b += __shfl_xor(sp1b, 32);
        sp2b += __shfl_xor(sp2b, 16); sp2b += __shfl_xor(sp2b, 32);
        if (quad == 0) {
            s1[row0 + l15] = sp1a; s2[row0 + l15] = sp2a;
            s1[row0 + 16 + l15] = sp1b; s2[row0 + 16 + l15] = sp2b;
        }
        float m = fmaxf(sp2a, sp2b);
#pragma unroll
        for (int off = 1; off <= 8; off <<= 1) m = fmaxf(m, __shfl_xor(m, off));
        if (lane == 0) {
            unsigned bt = __float_as_uint(m);
            unsigned keyv = (bt & 0x80000000u) ? ~bt : (bt | 0x80000000u);
            atomicMax(&s2maxkey[row0 >> 10], keyv);
        }
    }
}

// ---------------------------------------------------------------------------
// P producer in A-FRAG order: pA[b][it][jt][lane][8]; plane-packed mask words.
__global__ __launch_bounds__(256) void k_pgen(const float* __restrict__ s1, const float* __restrict__ s2,
                                              const unsigned* __restrict__ mask32,
                                              const unsigned* __restrict__ s2maxkey,
                                              _Float16* __restrict__ pA, float* __restrict__ lsums) {
    __shared__ float s2s[N];
    __shared__ float lp[4][16];
    const int lin = blockIdx.x;                    // 512 blocks
    const int xcd = lin & 7, sl = lin >> 3;
    const int b = xcd * 2 + (sl & 1);
    const int itg = sl >> 1;                       // 0..31
    const int t = threadIdx.x;
    const int lane = t & 63, w = t >> 6;
    const int l15 = lane & 15, quad = lane >> 4;

    unsigned key = s2maxkey[b];
    unsigned mb = (key & 0x80000000u) ? (key ^ 0x80000000u) : ~key;
    const float s2max = __uint_as_float(mb);
    for (int idx = t; idx < N; idx += 256) s2s[idx] = s2[b * N + idx];
    __syncthreads();

    const int it = itg * 2 + (w & 1);
    const int jt0 = (w >> 1) * 16;
    const int i = it * 16 + l15;
    const float s1v = s1[b * N + i];
    const float tmx = s1v + s2max;
    const float mrow = fmaxf(tmx, ALPHA * tmx);
    const unsigned* mp = mask32 + (size_t)(b * N + i) * 32;
    _Float16* pdst = pA + (size_t)(((b * 64 + it) * 32 + jt0) * 64) * 8 + lane * 8;
    const int qsh = quad * 2;
    float lacc = 0.f;

    for (int jl = 0; jl < 16; jl++) {
        const int jt = jt0 + jl;
        unsigned mw = mp[jt];
        float4 sa = *(const float4*)&s2s[jt * 32 + quad * 8];
        float4 sb = *(const float4*)&s2s[jt * 32 + quad * 8 + 4];
        float sv[8] = {sa.x, sa.y, sa.z, sa.w, sb.x, sb.y, sb.z, sb.w};
        union { _Float16 h[8]; half8 v; } pk;
#pragma unroll
        for (int jj = 0; jj < 8; jj++) {
            float e = s1v + sv[jj];
            e = fmaxf(e, ALPHA * e);
            float p = __expf(e - mrow);
            // plane-packed bit: (jj&3)*8 + (jj>>2) + quad*2
            p = ((mw >> ((jj & 3) * 8 + (jj >> 2) + qsh)) & 1u) ? p : 0.f;
            pk.h[jj] = (_Float16)p;
            lacc += (float)pk.h[jj];
        }
        *(half8*)(pdst + (size_t)jl * 512) = pk.v;
    }
    lacc += __shfl_xor(lacc, 16);
    lacc += __shfl_xor(lacc, 32);
    if (quad == 0) lp[w][l15] = lacc;
    __syncthreads();
    if (t < 32) {
        int itl = t >> 4, lf = t & 15;
        float tot = lp[itl][lf] + lp[2 + itl][lf];
        lsums[b * N + (itg * 2 + itl) * 16 + lf] = tot;
    }
}

// ---------------------------------------------------------------------------
// GAT: out = relu((P @ h)/l). Pure f16 GEMM, ALL loads lane-sequential frag
// blocks (1KB coalesced). Zero LDS/barriers, depth-2 prefetch. 64i x 128c.
template <int LAST>
__global__ __launch_bounds__(256, 2) void k_gat(const _Float16* __restrict__ pA,
                                                const _Float16* __restrict__ hB,
                                                const float* __restrict__ lsums,
                                                float* __restrict__ outf,
                                                ushort* __restrict__ oxhi, ushort* __restrict__ oxlo,
                                                float* __restrict__ psum, float* __restrict__ pmax) {
    const int lin = blockIdx.x;                     // 512 blocks
    const int xcd = lin & 7, sl = lin >> 3;
    const int b = xcd * 2 + (sl & 1);
    const int chunk = (sl >> 1) & 15;
    const int chalf = sl >> 5;
    const int i0 = chunk * 64;
    const int t = threadIdx.x;
    const int lane = t & 63, w = t >> 6;
    const int l15 = lane & 15, quad = lane >> 4;
    const int nb = 2 * w;
    const int ct0 = chalf * 8 + nb;

    const _Float16* pa0 = pA + (size_t)((b * 64 + chunk * 4 + 0) * 32 * 64) * 8 + lane * 8;
    const _Float16* pa1 = pA + (size_t)((b * 64 + chunk * 4 + 1) * 32 * 64) * 8 + lane * 8;
    const _Float16* pa2 = pA + (size_t)((b * 64 + chunk * 4 + 2) * 32 * 64) * 8 + lane * 8;
    const _Float16* pa3 = pA + (size_t)((b * 64 + chunk * 4 + 3) * 32 * 64) * 8 + lane * 8;
    const _Float16* pb0 = hB + (size_t)((b * 16 + ct0) * 32 * 64) * 8 + lane * 8;
    const _Float16* pb1 = hB + (size_t)((b * 16 + ct0 + 1) * 32 * 64) * 8 + lane * 8;

    floatx4 acc[4][2];
    floatx4 z = {0.f, 0.f, 0.f, 0.f};
#pragma unroll
    for (int rg = 0; rg < 4; rg++) { acc[rg][0] = z; acc[rg][1] = z; }

    half8 cA0 = *(const half8*)(pa0), cA1 = *(const half8*)(pa1);
    half8 cA2 = *(const half8*)(pa2), cA3 = *(const half8*)(pa3);
    half8 cB0 = *(const half8*)(pb0), cB1 = *(const half8*)(pb1);
    half8 nA0 = *(const half8*)(pa0 + 512), nA1 = *(const half8*)(pa1 + 512);
    half8 nA2 = *(const half8*)(pa2 + 512), nA3 = *(const half8*)(pa3 + 512);
    half8 nB0 = *(const half8*)(pb0 + 512), nB1 = *(const half8*)(pb1 + 512);

#pragma unroll 2
    for (int jt = 0; jt < 32; jt++) {
        const int j2 = (jt + 2 <= 31 ? jt + 2 : 31) * 512;
        half8 fA0 = *(const half8*)(pa0 + j2);
        half8 fA1 = *(const half8*)(pa1 + j2);
        half8 fA2 = *(const half8*)(pa2 + j2);
        half8 fA3 = *(const half8*)(pa3 + j2);
        half8 fB0 = *(const half8*)(pb0 + j2);
        half8 fB1 = *(const half8*)(pb1 + j2);
        acc[0][0] = mfma_f16(cA0, cB0, acc[0][0]);
        acc[1][0] = mfma_f16(cA1, cB0, acc[1][0]);
        acc[2][0] = mfma_f16(cA2, cB0, acc[2][0]);
        acc[3][0] = mfma_f16(cA3, cB0, acc[3][0]);
        acc[0][1] = mfma_f16(cA0, cB1, acc[0][1]);
        acc[1][1] = mfma_f16(cA1, cB1, acc[1][1]);
        acc[2][1] = mfma_f16(cA2, cB1, acc[2][1]);
        acc[3][1] = mfma_f16(cA3, cB1, acc[3][1]);
        cA0 = nA0; cA1 = nA1; cA2 = nA2; cA3 = nA3; cB0 = nB0; cB1 = nB1;
        nA0 = fA0; nA1 = fA1; nA2 = fA2; nA3 = fA3; nB0 = fB0; nB1 = fB1;
    }

    const size_t rbase = (size_t)b * N + i0;
    float inv[4][4];
#pragma unroll
    for (int rg = 0; rg < 4; rg++)
#pragma unroll
        for (int r = 0; r < 4; r++) inv[rg][r] = 1.f / lsums[rbase + rg * 16 + quad * 4 + r];

    float colsum[2] = {0.f, 0.f}, colmax[2] = {-INFINITY, -INFINITY};
#pragma unroll
    for (int rg = 0; rg < 4; rg++)
#pragma unroll
        for (int n2 = 0; n2 < 2; n2++) {
            const int c = (ct0 + n2) * 16 + l15;
#pragma unroll
            for (int r = 0; r < 4; r++) {
                float v = fmaxf(acc[rg][n2][r] * inv[rg][r], 0.f);
                const size_t row = rbase + rg * 16 + quad * 4 + r;
                if (LAST) {
                    outf[row * H + c] = v;
                    colsum[n2] += v;
                    colmax[n2] = fmaxf(colmax[n2], v);
                } else {
                    unsigned hi = rne_hi(v);
                    oxhi[row * H + c] = (ushort)hi;
                    oxlo[row * H + c] = (ushort)rne_hi(v - bf16val(hi));
                }
            }
        }
    if (LAST) {
#pragma unroll
        for (int n2 = 0; n2 < 2; n2++) {
            float s = colsum[n2], m = colmax[n2];
            s += __shfl_xor(s, 16); s += __shfl_xor(s, 32);
            m = fmaxf(m, __shfl_xor(m, 16)); m = fmaxf(m, __shfl_xor(m, 32));
            if (quad == 0) {
                const int c = (ct0 + n2) * 16 + l15;
                psum[(b * 16 + chunk) * H + c] = s;
                pmax[(b * 16 + chunk) * H + c] = m;
            }
        }
    }
}

// ---------------------------------------------------------------------------
// finish mean+max over 16 chunk-partials, then 2-layer MLP -> g[b,:]
__global__ __launch_bounds__(256) void k_pool2(const float* __restrict__ psum,
                                               const float* __restrict__ pmax,
                                               const float* __restrict__ W1, const float* __restrict__ b1,
                                               const float* __restrict__ W2, const float* __restrict__ b2,
                                               float* __restrict__ gout) {
    __shared__ float g_s[H];
    __shared__ float t_s[H];
    const int b = blockIdx.x;
    const int c = threadIdx.x;
    float s = 0.f, m = -INFINITY;
#pragma unroll
    for (int ch = 0; ch < 16; ch++) {
        s += psum[(b * 16 + ch) * H + c];
        m = fmaxf(m, pmax[(b * 16 + ch) * H + c]);
    }
    g_s[c] = s * (1.f / N) + m;
    __syncthreads();
    float a = b1[c];
#pragma unroll 16
    for (int k = 0; k < H; k++) a += g_s[k] * W1[k * H + c];
    t_s[c] = fmaxf(a, 0.f);
    __syncthreads();
    float o = b2[c];
#pragma unroll 16
    for (int k = 0; k < H; k++) o += t_s[k] * W2[k * H + c];
    gout[b * H + c] = o;
}

// ---------------------------------------------------------------------------
extern "C" void kernel_launch(void* const* d_in, const int* in_sizes, int n_in,
                              void* d_out, int out_size, void* d_ws, size_t ws_size,
                              hipStream_t stream) {
    const float* nf    = (const float*)d_in[0];
    const float* adj   = (const float*)d_in[1];
    const float* emb_W = (const float*)d_in[2];
    const float* emb_b = (const float*)d_in[3];
    const float* W0    = (const float*)d_in[4];
    const float* a1_0  = (const float*)d_in[5];
    const float* a2_0  = (const float*)d_in[6];
    const float* W1    = (const float*)d_in[7];
    const float* a1_1  = (const float*)d_in[8];
    const float* a2_1  = (const float*)d_in[9];
    const float* gpW1  = (const float*)d_in[10];
    const float* gpb1  = (const float*)d_in[11];
    const float* gpW2  = (const float*)d_in[12];
    const float* gpb2  = (const float*)d_in[13];

    float* xout = (float*)d_out;
    float* gout = xout + B * N * H;

    char* w = (char*)d_ws;
    ushort* xhi      = (ushort*)(w);                  //  8 MB
    ushort* xlo      = (ushort*)(w + 8388608);        //  8 MB
    _Float16* hB     = (_Float16*)(w + 16777216);     //  8 MB (B-frag order)
    _Float16* pA     = (_Float16*)(w + 25165824);     // 32 MB (A-frag order)
    unsigned* mask32 = (unsigned*)(w + 58720256);     //  2 MB (plane-packed)
    float* s1        = (float*)(w + 60817408);
    float* s2        = (float*)(w + 60882944);
    float* lsums     = (float*)(w + 60948480);
    ushort* wBh      = (ushort*)(w + 61013504);       // 256 KB (B-frag order)
    ushort* wBl      = (ushort*)(w + 61275648);       // 256 KB
    float* wa1       = (float*)(w + 61537792);
    float* wa2       = (float*)(w + 61539840);
    unsigned* keys   = (unsigned*)(w + 61541888);
    // psum/pmax overlay xhi (dead after gemm<1> staging; written by gat<1>)
    float* psum      = (float*)(w);
    float* pmax      = (float*)(w + 262144);

    hipMemsetAsync(keys, 0, 128, stream);
    k_front<<<1570, 256, 0, stream>>>(adj, nf, emb_W, emb_b, W0, W1,
                                      a1_0, a2_0, a1_1, a2_1,
                                      mask32, xhi, xlo, wBh, wBl, wa1, wa2);

    // layer 0
    k_gemm<<<1024, 256, 0, stream>>>(xhi, xlo, wBh, wBl, wa1, wa2, hB, s1, s2, keys);
    k_pgen<<<512, 256, 0, stream>>>(s1, s2, mask32, keys, pA, lsums);
    k_gat<0><<<512, 256, 0, stream>>>(pA, hB, lsums, nullptr, xhi, xlo, nullptr, nullptr);

    // layer 1
    k_gemm<<<1024, 256, 0, stream>>>(xhi, xlo, wBh + 65536, wBl + 65536, wa1 + H, wa2 + H,
                                     hB, s1, s2, keys + 16);
    k_pgen<<<512, 256, 0, stream>>>(s1, s2, mask32, keys + 16, pA, lsums);
    k_gat<1><<<512, 256, 0, stream>>>(pA, hB, lsums, xout, nullptr, nullptr, psum, pmax);

    // pooling MLP
    k_pool2<<<B, 256, 0, stream>>>(psum, pmax, gpW1, gpb1, gpW2, gpb2, gout);
}

// Round 9
// 243.802 us; speedup vs baseline: 1.5471x; 1.0429x over previous
//
#include <hip/hip_runtime.h>
#include <hip/hip_bf16.h>

#define B 16
#define N 1024
#define F_IN 64
#define H 256
#define ALPHA 0.2f

typedef __attribute__((ext_vector_type(8))) short short8;
typedef __attribute__((ext_vector_type(8))) _Float16 half8;
typedef __attribute__((ext_vector_type(4))) _Float16 half4;
typedef __attribute__((ext_vector_type(4))) float floatx4;

__device__ __forceinline__ floatx4 mfma_f16(half8 a, half8 b, floatx4 c) {
    return __builtin_amdgcn_mfma_f32_16x16x32_f16(a, b, c, 0, 0, 0);
}

// ---------------------------------------------------------------------------
// Fused front kernel:
//   blocks [0,1024):    adj -> bitmask, plane-packed words (see pgen extract)
//   blocks [1024,1536): embed (32 rows/block, nf in LDS, W col reuse x32) -> f16 x
//   blocks [1536,1570): W -> B-frag f16 (32) ; wa = W@a (2)
// mask32[(b*N+i)*32 + jt], bit (k*8+m) <-> j offset m*4+k within the 32-j word
__global__ __launch_bounds__(256) void k_front(const float* __restrict__ adj,
                                               const float* __restrict__ nf,
                                               const float* __restrict__ embW,
                                               const float* __restrict__ embB,
                                               const float* __restrict__ W0, const float* __restrict__ W1,
                                               const float* __restrict__ a10, const float* __restrict__ a20,
                                               const float* __restrict__ a11, const float* __restrict__ a21,
                                               unsigned* __restrict__ mask32,
                                               _Float16* __restrict__ xf,
                                               _Float16* __restrict__ wBf,
                                               float* __restrict__ wa1, float* __restrict__ wa2) {
    __shared__ float lds[256 * 17];
    const int blk = blockIdx.x;
    const int t = threadIdx.x;
    const int lane = t & 63;

    if (blk < 1024) {
        // ---- mask: wave handles 256 j per task via float4 + 4 ballots ----
        const int wv = blk * 4 + (t >> 6);
#pragma unroll 2
        for (int task = wv; task < B * N * 4; task += 4096) {
            const float4 v = *(const float4*)(adj + (size_t)task * 256 + lane * 4);
            unsigned long long b0 = __ballot(v.x > 0.f);
            unsigned long long b1 = __ballot(v.y > 0.f);
            unsigned long long b2 = __ballot(v.z > 0.f);
            unsigned long long b3 = __ballot(v.w > 0.f);
            if (lane < 8) {
                unsigned w0 = (unsigned)((b0 >> (8 * lane)) & 0xff)
                            | ((unsigned)((b1 >> (8 * lane)) & 0xff) << 8)
                            | ((unsigned)((b2 >> (8 * lane)) & 0xff) << 16)
                            | ((unsigned)((b3 >> (8 * lane)) & 0xff) << 24);
                const int jg = task & 3, row = task >> 2;
                mask32[(size_t)row * 32 + jg * 8 + lane] = w0;
            }
        }
        return;
    }
    if (blk < 1536) {
        // ---- embed: 32 rows/block, f16 output ----
        const int row0 = (blk - 1024) * 32;
        float* nfs = lds;                       // [f][32]
        for (int idx = t; idx < 32 * F_IN; idx += 256) {
            int r = idx >> 6, f = idx & 63;
            nfs[f * 32 + r] = nf[(size_t)(row0 + r) * F_IN + f];
        }
        __syncthreads();
        const int c = t;
        float acc[32];
        const float bv = embB[c];
#pragma unroll
        for (int r = 0; r < 32; r++) acc[r] = bv;
#pragma unroll 8
        for (int f = 0; f < F_IN; f++) {
            const float w = embW[f * H + c];
            const float* nrow = nfs + f * 32;
#pragma unroll
            for (int q = 0; q < 8; q++) {
                float4 n4 = *(const float4*)(nrow + q * 4);
                acc[q * 4 + 0] += n4.x * w;
                acc[q * 4 + 1] += n4.y * w;
                acc[q * 4 + 2] += n4.z * w;
                acc[q * 4 + 3] += n4.w * w;
            }
        }
#pragma unroll
        for (int r = 0; r < 32; r++)
            xf[(size_t)(row0 + r) * H + c] = (_Float16)acc[r];
        return;
    }
    // ---- prep ----
    const int pb = blk - 1536;
    if (pb >= 32) {
        const int l = pb - 32;
        const float* W = l ? W1 : W0;
        const float* a1 = l ? a11 : a10;
        const float* a2 = l ? a21 : a20;
        float* a1s = lds;
        float* a2s = lds + 256;
        a1s[t] = a1[t]; a2s[t] = a2[t];
        __syncthreads();
        float v1 = 0.f, v2 = 0.f;
        for (int c = 0; c < H; c += 4) {
            float4 w = *(const float4*)&W[t * H + c];
            v1 += w.x * a1s[c] + w.y * a1s[c + 1] + w.z * a1s[c + 2] + w.w * a1s[c + 3];
            v2 += w.x * a2s[c] + w.y * a2s[c + 1] + w.z * a2s[c + 2] + w.w * a2s[c + 3];
        }
        wa1[l * H + t] = v1;
        wa2[l * H + t] = v2;
        return;
    }
    const int l = pb >> 4, ct = pb & 15;
    const float* W = l ? W1 : W0;
#pragma unroll
    for (int rep = 0; rep < 16; rep++) {
        int idx = rep * 256 + t;
        int k = idx >> 4, cl = idx & 15;
        lds[k * 17 + cl] = W[k * H + ct * 16 + cl];
    }
    __syncthreads();
    const int w = t >> 6;
    const int l15 = lane & 15, quad = lane >> 4;
#pragma unroll
    for (int e = 0; e < 2; e++) {
        const int ks = w * 2 + e;
        half8 bf;
#pragma unroll
        for (int jj = 0; jj < 8; jj++)
            bf[jj] = (_Float16)lds[(ks * 32 + quad * 8 + jj) * 17 + l15];
        *(half8*)(wBf + (size_t)(((l * 16 + ct) * 8 + ks) * 64 + lane) * 8) = bf;
    }
}

// ---------------------------------------------------------------------------
// h = x @ W (pure f16 MFMA, 4/ks). x staged to LDS in A-frag order (1 barrier),
// W read as coalesced f16 B-frags from global, zero per-ks barriers. h stored
// to hB in B-frag order via LDS transpose. chalf0/w0: fp32 s1/s2 + s2max.
#define XS(it, ks) ((((it) * 8 + (ks))) * 520)
__global__ __launch_bounds__(256, 4) void k_gemm(const _Float16* __restrict__ xf,
                                                 const _Float16* __restrict__ wBf,
                                                 const float* __restrict__ wa1, const float* __restrict__ wa2,
                                                 _Float16* __restrict__ hB,
                                                 float* __restrict__ s1, float* __restrict__ s2,
                                                 unsigned* __restrict__ s2maxkey) {
    __shared__ __align__(16) _Float16 sm[8320];     // x frags; reused for transpose
    const int lin = blockIdx.x;
    const int rc = lin >> 1, chalf = lin & 1;
    const int row0 = rc * 32;
    const int t = threadIdx.x;
    const int lane = t & 63, w = t >> 6;
    const int l15 = lane & 15, quad = lane >> 4;

    // ---- stage x into LDS in A-frag order ----
#pragma unroll
    for (int pass = 0; pass < 4; pass++) {
        int idx = pass * 256 + t;
        int row_l = idx >> 5, k8 = idx & 31;
        half8 v = *(const half8*)(xf + (size_t)(row0 + row_l) * H + k8 * 8);
        int it = row_l >> 4, lf = row_l & 15, ks = k8 >> 2, qd = k8 & 3;
        *(half8*)(sm + XS(it, ks) + (qd * 16 + lf) * 8) = v;
    }
    __syncthreads();

    const int ct0 = chalf * 8 + 2 * w;
    const _Float16* pB0 = wBf + (size_t)((ct0 * 8) * 64 + lane) * 8;
    const _Float16* pB1 = wBf + (size_t)(((ct0 + 1) * 8) * 64 + lane) * 8;

    floatx4 acc[2][2];
    floatx4 z = {0.f, 0.f, 0.f, 0.f};
    acc[0][0] = z; acc[0][1] = z; acc[1][0] = z; acc[1][1] = z;
    float sp1a = 0.f, sp2a = 0.f, sp1b = 0.f, sp2b = 0.f;

    half8 B0 = *(const half8*)(pB0);
    half8 B1 = *(const half8*)(pB1);

#pragma unroll
    for (int ks = 0; ks < 8; ks++) {
        half8 nB0 = B0, nB1 = B1;
        if (ks < 7) {
            const int o = (ks + 1) * 512;
            nB0 = *(const half8*)(pB0 + o);
            nB1 = *(const half8*)(pB1 + o);
        }
        half8 A0 = *(const half8*)(sm + XS(0, ks) + lane * 8);
        half8 A1 = *(const half8*)(sm + XS(1, ks) + lane * 8);
        acc[0][0] = mfma_f16(A0, B0, acc[0][0]);
        acc[0][1] = mfma_f16(A0, B1, acc[0][1]);
        acc[1][0] = mfma_f16(A1, B0, acc[1][0]);
        acc[1][1] = mfma_f16(A1, B1, acc[1][1]);
        if (chalf == 0 && w == 0) {
            float4 w1a = *(const float4*)(wa1 + ks * 32 + quad * 8);
            float4 w1b = *(const float4*)(wa1 + ks * 32 + quad * 8 + 4);
            float4 w2a = *(const float4*)(wa2 + ks * 32 + quad * 8);
            float4 w2b = *(const float4*)(wa2 + ks * 32 + quad * 8 + 4);
            float wv1[8] = {w1a.x, w1a.y, w1a.z, w1a.w, w1b.x, w1b.y, w1b.z, w1b.w};
            float wv2[8] = {w2a.x, w2a.y, w2a.z, w2a.w, w2b.x, w2b.y, w2b.z, w2b.w};
#pragma unroll
            for (int j = 0; j < 8; j++) {
                float xa = (float)A0[j];
                float xb = (float)A1[j];
                sp1a += xa * wv1[j]; sp2a += xa * wv2[j];
                sp1b += xb * wv1[j]; sp2b += xb * wv2[j];
            }
        }
        B0 = nB0; B1 = nB1;
    }

    // ---- epilogue: f16 + LDS transpose -> B-frag order hB stores ----
    __syncthreads();
    _Float16* trc = sm;                         // [c_local(128)][40]
#pragma unroll
    for (int rg = 0; rg < 2; rg++) {
#pragma unroll
        for (int n2 = 0; n2 < 2; n2++) {
            const int c_l = (2 * w + n2) * 16 + l15;
            half4 hv;
            hv[0] = (_Float16)acc[rg][n2][0];
            hv[1] = (_Float16)acc[rg][n2][1];
            hv[2] = (_Float16)acc[rg][n2][2];
            hv[3] = (_Float16)acc[rg][n2][3];
            *(half4*)(trc + c_l * 40 + rg * 16 + quad * 4) = hv;
        }
    }
    __syncthreads();
    {
        const int ct_l = t >> 5, sub = t & 31;
        const int bb = row0 >> 10, jt = (row0 >> 5) & 31;
        _Float16* dst = hB + (size_t)(((bb * 16 + chalf * 8 + ct_l) * 32 + jt) * 64) * 8;
#pragma unroll
        for (int rep = 0; rep < 2; rep++) {
            int lo = sub + rep * 32;
            int qd = lo >> 4, lf = lo & 15;
            half8 hv = *(const half8*)(trc + (ct_l * 16 + lf) * 40 + qd * 8);
            *(half8*)(dst + lo * 8) = hv;
        }
    }
    // ---- s1/s2 (fp32 x.wa) ----
    if (chalf == 0 && w == 0) {
        sp1a += __shfl_xor(sp1a, 16); sp1a += __shfl_xor(sp1a, 32);
        sp2a += __shfl_xor(sp2a, 16); sp2a += __shfl_xor(sp2a, 32);
        sp1b += __shfl_xor(sp1b, 16); sp1b += __shfl_xor(sp1b, 32);
        sp2b += __shfl_xor(sp2b, 16); sp2b += __shfl_xor(sp2b, 32);
        if (quad == 0) {
            s1[row0 + l15] = sp1a; s2[row0 + l15] = sp2a;
            s1[row0 + 16 + l15] = sp1b; s2[row0 + 16 + l15] = sp2b;
        }
        float m = fmaxf(sp2a, sp2b);
#pragma unroll
        for (int off = 1; off <= 8; off <<= 1) m = fmaxf(m, __shfl_xor(m, off));
        if (lane == 0) {
            unsigned bt = __float_as_uint(m);
            unsigned keyv = (bt & 0x80000000u) ? ~bt : (bt | 0x80000000u);
            atomicMax(&s2maxkey[row0 >> 10], keyv);
        }
    }
}

// ---------------------------------------------------------------------------
// P producer in A-FRAG order: pA[b][it][jt][lane][8]; plane-packed mask words.
__global__ __launch_bounds__(256) void k_pgen(const float* __restrict__ s1, const float* __restrict__ s2,
                                              const unsigned* __restrict__ mask32,
                                              const unsigned* __restrict__ s2maxkey,
                                              _Float16* __restrict__ pA, float* __restrict__ lsums) {
    __shared__ float s2s[N];
    __shared__ float lp[4][16];
    const int lin = blockIdx.x;                    // 512 blocks
    const int xcd = lin & 7, sl = lin >> 3;
    const int b = xcd * 2 + (sl & 1);
    const int itg = sl >> 1;                       // 0..31
    const int t = threadIdx.x;
    const int lane = t & 63, w = t >> 6;
    const int l15 = lane & 15, quad = lane >> 4;

    unsigned key = s2maxkey[b];
    unsigned mb = (key & 0x80000000u) ? (key ^ 0x80000000u) : ~key;
    const float s2max = __uint_as_float(mb);
    for (int idx = t; idx < N; idx += 256) s2s[idx] = s2[b * N + idx];
    __syncthreads();

    const int it = itg * 2 + (w & 1);
    const int jt0 = (w >> 1) * 16;
    const int i = it * 16 + l15;
    const float s1v = s1[b * N + i];
    const float tmx = s1v + s2max;
    const float mrow = fmaxf(tmx, ALPHA * tmx);
    const unsigned* mp = mask32 + (size_t)(b * N + i) * 32;
    _Float16* pdst = pA + (size_t)(((b * 64 + it) * 32 + jt0) * 64) * 8 + lane * 8;
    const int qsh = quad * 2;
    float lacc = 0.f;

    for (int jl = 0; jl < 16; jl++) {
        const int jt = jt0 + jl;
        unsigned mw = mp[jt];
        float4 sa = *(const float4*)&s2s[jt * 32 + quad * 8];
        float4 sb = *(const float4*)&s2s[jt * 32 + quad * 8 + 4];
        float sv[8] = {sa.x, sa.y, sa.z, sa.w, sb.x, sb.y, sb.z, sb.w};
        union { _Float16 h[8]; half8 v; } pk;
#pragma unroll
        for (int jj = 0; jj < 8; jj++) {
            float e = s1v + sv[jj];
            e = fmaxf(e, ALPHA * e);
            float p = __expf(e - mrow);
            // plane-packed bit: (jj&3)*8 + (jj>>2) + quad*2
            p = ((mw >> ((jj & 3) * 8 + (jj >> 2) + qsh)) & 1u) ? p : 0.f;
            pk.h[jj] = (_Float16)p;
            lacc += (float)pk.h[jj];
        }
        *(half8*)(pdst + (size_t)jl * 512) = pk.v;
    }
    lacc += __shfl_xor(lacc, 16);
    lacc += __shfl_xor(lacc, 32);
    if (quad == 0) lp[w][l15] = lacc;
    __syncthreads();
    if (t < 32) {
        int itl = t >> 4, lf = t & 15;
        float tot = lp[itl][lf] + lp[2 + itl][lf];
        lsums[b * N + (itg * 2 + itl) * 16 + lf] = tot;
    }
}

// ---------------------------------------------------------------------------
// GAT: out = relu((P @ h)/l). Pure f16 GEMM, ALL loads lane-sequential frag
// blocks (1KB coalesced). Zero LDS/barriers, depth-2 prefetch. 64i x 128c.
template <int LAST>
__global__ __launch_bounds__(256, 2) void k_gat(const _Float16* __restrict__ pA,
                                                const _Float16* __restrict__ hB,
                                                const float* __restrict__ lsums,
                                                float* __restrict__ outf,
                                                _Float16* __restrict__ oxf,
                                                float* __restrict__ psum, float* __restrict__ pmax) {
    const int lin = blockIdx.x;                     // 512 blocks
    const int xcd = lin & 7, sl = lin >> 3;
    const int b = xcd * 2 + (sl & 1);
    const int chunk = (sl >> 1) & 15;
    const int chalf = sl >> 5;
    const int i0 = chunk * 64;
    const int t = threadIdx.x;
    const int lane = t & 63, w = t >> 6;
    const int l15 = lane & 15, quad = lane >> 4;
    const int nb = 2 * w;
    const int ct0 = chalf * 8 + nb;

    const _Float16* pa0 = pA + (size_t)((b * 64 + chunk * 4 + 0) * 32 * 64) * 8 + lane * 8;
    const _Float16* pa1 = pA + (size_t)((b * 64 + chunk * 4 + 1) * 32 * 64) * 8 + lane * 8;
    const _Float16* pa2 = pA + (size_t)((b * 64 + chunk * 4 + 2) * 32 * 64) * 8 + lane * 8;
    const _Float16* pa3 = pA + (size_t)((b * 64 + chunk * 4 + 3) * 32 * 64) * 8 + lane * 8;
    const _Float16* pb0 = hB + (size_t)((b * 16 + ct0) * 32 * 64) * 8 + lane * 8;
    const _Float16* pb1 = hB + (size_t)((b * 16 + ct0 + 1) * 32 * 64) * 8 + lane * 8;

    floatx4 acc[4][2];
    floatx4 z = {0.f, 0.f, 0.f, 0.f};
#pragma unroll
    for (int rg = 0; rg < 4; rg++) { acc[rg][0] = z; acc[rg][1] = z; }

    half8 cA0 = *(const half8*)(pa0), cA1 = *(const half8*)(pa1);
    half8 cA2 = *(const half8*)(pa2), cA3 = *(const half8*)(pa3);
    half8 cB0 = *(const half8*)(pb0), cB1 = *(const half8*)(pb1);
    half8 nA0 = *(const half8*)(pa0 + 512), nA1 = *(const half8*)(pa1 + 512);
    half8 nA2 = *(const half8*)(pa2 + 512), nA3 = *(const half8*)(pa3 + 512);
    half8 nB0 = *(const half8*)(pb0 + 512), nB1 = *(const half8*)(pb1 + 512);

#pragma unroll 2
    for (int jt = 0; jt < 32; jt++) {
        const int j2 = (jt + 2 <= 31 ? jt + 2 : 31) * 512;
        half8 fA0 = *(const half8*)(pa0 + j2);
        half8 fA1 = *(const half8*)(pa1 + j2);
        half8 fA2 = *(const half8*)(pa2 + j2);
        half8 fA3 = *(const half8*)(pa3 + j2);
        half8 fB0 = *(const half8*)(pb0 + j2);
        half8 fB1 = *(const half8*)(pb1 + j2);
        acc[0][0] = mfma_f16(cA0, cB0, acc[0][0]);
        acc[1][0] = mfma_f16(cA1, cB0, acc[1][0]);
        acc[2][0] = mfma_f16(cA2, cB0, acc[2][0]);
        acc[3][0] = mfma_f16(cA3, cB0, acc[3][0]);
        acc[0][1] = mfma_f16(cA0, cB1, acc[0][1]);
        acc[1][1] = mfma_f16(cA1, cB1, acc[1][1]);
        acc[2][1] = mfma_f16(cA2, cB1, acc[2][1]);
        acc[3][1] = mfma_f16(cA3, cB1, acc[3][1]);
        cA0 = nA0; cA1 = nA1; cA2 = nA2; cA3 = nA3; cB0 = nB0; cB1 = nB1;
        nA0 = fA0; nA1 = fA1; nA2 = fA2; nA3 = fA3; nB0 = fB0; nB1 = fB1;
    }

    const size_t rbase = (size_t)b * N + i0;
    float inv[4][4];
#pragma unroll
    for (int rg = 0; rg < 4; rg++)
#pragma unroll
        for (int r = 0; r < 4; r++) inv[rg][r] = 1.f / lsums[rbase + rg * 16 + quad * 4 + r];

    float colsum[2] = {0.f, 0.f}, colmax[2] = {-INFINITY, -INFINITY};
#pragma unroll
    for (int rg = 0; rg < 4; rg++)
#pragma unroll
        for (int n2 = 0; n2 < 2; n2++) {
            const int c = (ct0 + n2) * 16 + l15;
#pragma unroll
            for (int r = 0; r < 4; r++) {
                float v = fmaxf(acc[rg][n2][r] * inv[rg][r], 0.f);
                const size_t row = rbase + rg * 16 + quad * 4 + r;
                if (LAST) {
                    outf[row * H + c] = v;
                    colsum[n2] += v;
                    colmax[n2] = fmaxf(colmax[n2], v);
                } else {
                    oxf[row * H + c] = (_Float16)v;
                }
            }
        }
    if (LAST) {
#pragma unroll
        for (int n2 = 0; n2 < 2; n2++) {
            float s = colsum[n2], m = colmax[n2];
            s += __shfl_xor(s, 16); s += __shfl_xor(s, 32);
            m = fmaxf(m, __shfl_xor(m, 16)); m = fmaxf(m, __shfl_xor(m, 32));
            if (quad == 0) {
                const int c = (ct0 + n2) * 16 + l15;
                psum[(b * 16 + chunk) * H + c] = s;
                pmax[(b * 16 + chunk) * H + c] = m;
            }
        }
    }
}

// ---------------------------------------------------------------------------
// finish mean+max over 16 chunk-partials, then 2-layer MLP -> g[b,:]
__global__ __launch_bounds__(256) void k_pool2(const float* __restrict__ psum,
                                               const float* __restrict__ pmax,
                                               const float* __restrict__ W1, const float* __restrict__ b1,
                                               const float* __restrict__ W2, const float* __restrict__ b2,
                                               float* __restrict__ gout) {
    __shared__ float g_s[H];
    __shared__ float t_s[H];
    const int b = blockIdx.x;
    const int c = threadIdx.x;
    float s = 0.f, m = -INFINITY;
#pragma unroll
    for (int ch = 0; ch < 16; ch++) {
        s += psum[(b * 16 + ch) * H + c];
        m = fmaxf(m, pmax[(b * 16 + ch) * H + c]);
    }
    g_s[c] = s * (1.f / N) + m;
    __syncthreads();
    float a = b1[c];
#pragma unroll 16
    for (int k = 0; k < H; k++) a += g_s[k] * W1[k * H + c];
    t_s[c] = fmaxf(a, 0.f);
    __syncthreads();
    float o = b2[c];
#pragma unroll 16
    for (int k = 0; k < H; k++) o += t_s[k] * W2[k * H + c];
    gout[b * H + c] = o;
}

// ---------------------------------------------------------------------------
extern "C" void kernel_launch(void* const* d_in, const int* in_sizes, int n_in,
                              void* d_out, int out_size, void* d_ws, size_t ws_size,
                              hipStream_t stream) {
    const float* nf    = (const float*)d_in[0];
    const float* adj   = (const float*)d_in[1];
    const float* emb_W = (const float*)d_in[2];
    const float* emb_b = (const float*)d_in[3];
    const float* W0    = (const float*)d_in[4];
    const float* a1_0  = (const float*)d_in[5];
    const float* a2_0  = (const float*)d_in[6];
    const float* W1    = (const float*)d_in[7];
    const float* a1_1  = (const float*)d_in[8];
    const float* a2_1  = (const float*)d_in[9];
    const float* gpW1  = (const float*)d_in[10];
    const float* gpb1  = (const float*)d_in[11];
    const float* gpW2  = (const float*)d_in[12];
    const float* gpb2  = (const float*)d_in[13];

    float* xout = (float*)d_out;
    float* gout = xout + B * N * H;

    char* w = (char*)d_ws;
    _Float16* xf     = (_Float16*)(w);                //  8 MB
    _Float16* hB     = (_Float16*)(w + 8388608);      //  8 MB (B-frag order)
    _Float16* pA     = (_Float16*)(w + 16777216);     // 32 MB (A-frag order)
    unsigned* mask32 = (unsigned*)(w + 50331648);     //  2 MB (plane-packed)
    float* s1        = (float*)(w + 52428800);
    float* s2        = (float*)(w + 52494336);
    float* lsums     = (float*)(w + 52559872);
    _Float16* wBf    = (_Float16*)(w + 52625408);     // 256 KB (B-frag, 2 layers)
    float* wa1       = (float*)(w + 52887552);
    float* wa2       = (float*)(w + 52889600);
    unsigned* keys   = (unsigned*)(w + 52891648);
    // psum/pmax overlay xf (dead after gemm<1> staging; written by gat<1>)
    float* psum      = (float*)(w);
    float* pmax      = (float*)(w + 262144);

    hipMemsetAsync(keys, 0, 128, stream);
    k_front<<<1570, 256, 0, stream>>>(adj, nf, emb_W, emb_b, W0, W1,
                                      a1_0, a2_0, a1_1, a2_1,
                                      mask32, xf, wBf, wa1, wa2);

    // layer 0
    k_gemm<<<1024, 256, 0, stream>>>(xf, wBf, wa1, wa2, hB, s1, s2, keys);
    k_pgen<<<512, 256, 0, stream>>>(s1, s2, mask32, keys, pA, lsums);
    k_gat<0><<<512, 256, 0, stream>>>(pA, hB, lsums, nullptr, xf, nullptr, nullptr);

    // layer 1
    k_gemm<<<1024, 256, 0, stream>>>(xf, wBf + 65536, wa1 + H, wa2 + H, hB, s1, s2, keys + 16);
    k_pgen<<<512, 256, 0, stream>>>(s1, s2, mask32, keys + 16, pA, lsums);
    k_gat<1><<<512, 256, 0, stream>>>(pA, hB, lsums, xout, nullptr, psum, pmax);

    // pooling MLP
    k_pool2<<<B, 256, 0, stream>>>(psum, pmax, gpW1, gpb1, gpW2, gpb2, gout);
}